// Round 4
// baseline (251.115 us; speedup 1.0000x reference)
//
#include <hip/hip_runtime.h>
#include <math.h>

#define B_SZ 16384
#define NQ 10
#define DEPTH 6

typedef float f32x2 __attribute__((ext_vector_type(2)));

__device__ __forceinline__ f32x2 bc(float x){ return (f32x2){x, x}; }
__device__ __forceinline__ f32x2 fma2(f32x2 a, f32x2 b, f32x2 c){
  return __builtin_elementwise_fma(a, b, c);
}

// ---- constexpr GF(2) tracking of the CNOT ring ----
struct Tables {
  int m[DEPTH][NQ];   // phys xor-mask for gate on logical q at layer d
  int R[DEPTH][NQ];   // logical bit q of phys p = parity(R & p)
  int meas[NQ];       // final-basis rows for measurement
};
constexpr Tables make_tables(){
  Tables t{};
  int cols[NQ] = {}, rows[NQ] = {};
  for (int i = 0; i < NQ; ++i){ cols[i] = 1 << i; rows[i] = 1 << i; }
  for (int d = 0; d < DEPTH; ++d){
    for (int q = 0; q < NQ; ++q){ t.m[d][q] = cols[q]; t.R[d][q] = rows[q]; }
    for (int c = 0; c < NQ; ++c){          // ring: (0,1)..(8,9),(9,0)
      int tt = (c + 1) % NQ;
      cols[c]  ^= cols[tt];
      rows[tt] ^= rows[c];
    }
  }
  for (int q = 0; q < NQ; ++q) t.meas[q] = rows[q];
  return t;
}
constexpr Tables TAB = make_tables();

// ---- monotone float<->uint key for atomicMax over signed floats ----
__device__ __forceinline__ unsigned fkey(float x){
  unsigned b = __float_as_uint(x);
  return (b & 0x80000000u) ? ~b : (b | 0x80000000u);
}
__device__ __forceinline__ float funkey(unsigned k){
  unsigned b = (k & 0x80000000u) ? (k ^ 0x80000000u) : ~k;
  return __uint_as_float(b);
}

// lane-xor exchange: DPP quad_perm for masks 1..3 (VALU pipe), shfl otherwise
template<int LM>
__device__ __forceinline__ float lanexor(float x){
  if constexpr (LM == 1 || LM == 2 || LM == 3){
    constexpr int ctrl = (0^LM) | ((1^LM)<<2) | ((2^LM)<<4) | ((3^LM)<<6);
    return __uint_as_float((unsigned)__builtin_amdgcn_update_dpp(
        0, (int)__float_as_uint(x), ctrl, 0xF, 0xF, true));
  } else {
    return __shfl_xor(x, LM, 64);
  }
}
template<int LM>
__device__ __forceinline__ f32x2 lx2(f32x2 v){
  f32x2 r;
  r.x = lanexor<LM>(v.x);
  r.y = lanexor<LM>(v.y);
  return r;
}

// ---- prep: layer-0 fused 1q unitaries, Rx coeffs, diagonal phase tables ----
__global__ __launch_bounds__(256) void k_prep(const float* __restrict__ wts,
    float4* __restrict__ U0,     // 20: q*2+{0:(u00,u01),1:(u10,u11)}
    float2* __restrict__ gc2,    // 50: (d-1)*10+q -> (cos ax, sin ax)
    float4* __restrict__ phase,  // 4*1024: layers 1..4 diagonal (c,c,s,s)
    unsigned* __restrict__ gkey)
{
  int idx = blockIdx.x * 256 + threadIdx.x;
  if (idx < 4096){
    int layer = 1 + (idx >> 10);
    int p = idx & 1023;
    float phi = 0.f;
    for (int q = 0; q < NQ; ++q){
      float az = wts[(layer*NQ + q)*2 + 1] * 0.5f;
      phi += (__popc(TAB.R[layer][q] & p) & 1) ? az : -az;
    }
    float c = cosf(phi), s = sinf(phi);
    phase[idx] = make_float4(c, c, s, s);
  }
  if (blockIdx.x == 0){
    int t = threadIdx.x;
    if (t < NQ){
      float ax = wts[t*2+0]*0.5f, az = wts[t*2+1]*0.5f;
      float ca=cosf(ax), sa=sinf(ax), cz=cosf(az), sz=sinf(az);
      U0[t*2+0] = make_float4(ca*cz, -ca*sz, -sa*sz, -sa*cz); // u00r,u00i,u01r,u01i
      U0[t*2+1] = make_float4(sa*sz, -sa*cz,  ca*cz,  ca*sz); // u10r,u10i,u11r,u11i
    } else if (t >= 64 && t < 64 + 50){
      int g = t - 64;                     // (d-1)*10+q, d=1..5
      int d = 1 + g/10, q = g - (d-1)*10;
      float ax = wts[(d*NQ+q)*2+0]*0.5f;
      gc2[g] = make_float2(cosf(ax), sinf(ax));
    } else if (t == 120){
      *gkey = 0u;
    }
  }
}

// ---- K1: pool -> encode -> global max ----
__global__ __launch_bounds__(256) void k1_encode(const float* __restrict__ x,
    const float* __restrict__ encW, const float* __restrict__ encB,
    float* __restrict__ encOut, unsigned* __restrict__ gkey)
{
  int s = blockIdx.x * 256 + threadIdx.x;
  const float* xs = x + (size_t)s * 784;
  float pool[16];
  #pragma unroll
  for (int i = 0; i < 16; ++i) pool[i] = 0.f;
  #pragma unroll
  for (int row = 0; row < 24; ++row){
    int p = row / 6;
    #pragma unroll
    for (int c4 = 0; c4 < 6; ++c4){
      float4 v = *reinterpret_cast<const float4*>(xs + row * 28 + c4 * 4);
      int c0 = c4 * 4;
      pool[p*4 + (c0+0)/6] += v.x;
      pool[p*4 + (c0+1)/6] += v.y;
      pool[p*4 + (c0+2)/6] += v.z;
      pool[p*4 + (c0+3)/6] += v.w;
    }
  }
  #pragma unroll
  for (int i = 0; i < 16; ++i) pool[i] *= (1.f/36.f);

  float m = -INFINITY;
  #pragma unroll
  for (int i = 0; i < NQ; ++i){
    float e = encB[i];
    #pragma unroll
    for (int k = 0; k < 16; ++k) e = fmaf(pool[k], encW[i*16+k], e);
    encOut[(size_t)s*NQ + i] = e;
    m = fmaxf(m, e);
  }
  #pragma unroll
  for (int st = 1; st < 64; st <<= 1) m = fmaxf(m, __shfl_xor(m, st, 64));
  __shared__ float wm[4];
  int lane = threadIdx.x & 63, w = threadIdx.x >> 6;
  if (lane == 0) wm[w] = m;
  __syncthreads();
  if (threadIdx.x == 0){
    float mm = fmaxf(fmaxf(wm[0], wm[1]), fmaxf(wm[2], wm[3]));
    atomicMax(gkey, fkey(mm));
  }
}

// ---- Rx gate on packed 2-sample state ----
template<int D, int Q>
__device__ __forceinline__ void rx_gate(f32x2 (&re)[16], f32x2 (&im)[16],
    const float2* __restrict__ gc2)
{
  constexpr int m  = TAB.m[D][Q];
  constexpr int rm = m & 15;
  constexpr int lm = m >> 4;
  float2 c = gc2[(D-1)*NQ + Q];     // wave-uniform -> s_load
  f32x2 ca = bc(c.x), sa = bc(c.y);
  f32x2 nsa = -sa;

  if constexpr (lm == 0){
    constexpr int lb = rm & (-rm);
    #pragma unroll
    for (int r = 0; r < 16; ++r) if (!(r & lb)){
      int r2 = r ^ rm;
      f32x2 ar = re[r],  ai = im[r];
      f32x2 br = re[r2], bi = im[r2];
      re[r]  = fma2(sa,  bi, ca*ar);
      im[r]  = fma2(nsa, br, ca*ai);
      re[r2] = fma2(sa,  ai, ca*br);
      im[r2] = fma2(nsa, ar, ca*bi);
    }
  } else if constexpr (rm == 0){
    #pragma unroll
    for (int r = 0; r < 16; ++r){
      f32x2 bi = lx2<lm>(im[r]);
      f32x2 br = lx2<lm>(re[r]);
      re[r] = fma2(sa,  bi, ca*re[r]);
      im[r] = fma2(nsa, br, ca*im[r]);
    }
  } else {
    constexpr int lb = rm & (-rm);
    #pragma unroll
    for (int r = 0; r < 16; ++r) if (!(r & lb)){
      int r2 = r ^ rm;
      f32x2 bi2 = lx2<lm>(im[r2]);
      f32x2 br2 = lx2<lm>(re[r2]);
      f32x2 bi1 = lx2<lm>(im[r]);
      f32x2 br1 = lx2<lm>(re[r]);
      re[r]  = fma2(sa,  bi2, ca*re[r]);
      im[r]  = fma2(nsa, br2, ca*im[r]);
      re[r2] = fma2(sa,  bi1, ca*re[r2]);
      im[r2] = fma2(nsa, br1, ca*im[r2]);
    }
  }
}

template<int D>
__device__ __forceinline__ void run_layer(f32x2 (&re)[16], f32x2 (&im)[16],
    const float2* __restrict__ gc2, const float4* __restrict__ phase4, int lane)
{
  rx_gate<D,0>(re, im, gc2);
  rx_gate<D,1>(re, im, gc2);
  rx_gate<D,2>(re, im, gc2);
  rx_gate<D,3>(re, im, gc2);
  rx_gate<D,4>(re, im, gc2);
  rx_gate<D,5>(re, im, gc2);
  rx_gate<D,6>(re, im, gc2);
  rx_gate<D,7>(re, im, gc2);
  rx_gate<D,8>(re, im, gc2);
  rx_gate<D,9>(re, im, gc2);
  if constexpr (D <= 4){
    const float4* __restrict__ pp = phase4 + (size_t)(D-1)*1024 + lane*16;
    #pragma unroll
    for (int r = 0; r < 16; ++r){
      float4 ph = pp[r];
      f32x2 cp = {ph.x, ph.y};
      f32x2 sp = {ph.z, ph.w};
      f32x2 ar = re[r], ai = im[r];
      re[r] = fma2(-sp, ai, cp*ar);
      im[r] = fma2( sp, ar, cp*ai);
    }
  }
  // D == 5: final diagonal dropped — phases don't affect |amp|^2
}

// ---- K2: one wave per TWO samples (packed in f32x2 components) ----
// amp index: bits[3:0] = register index, bits[9:4] = lane
__global__ __launch_bounds__(256) void k2_qsim(
    const float* __restrict__ enc, const unsigned* __restrict__ gkey,
    const float4* __restrict__ U0, const float2* __restrict__ gc2,
    const float4* __restrict__ phase4,
    const float* __restrict__ fcW, const float* __restrict__ fcB,
    float* __restrict__ outB)
{
  int tid  = threadIdx.x;
  int lane = tid & 63;
  int wid  = tid >> 6;
  int sA   = blockIdx.x * 8 + wid * 2;
  int sB   = sA + 1;

  float invr = 3.14159265358979f / (funkey(*gkey) + 1e-8f); // half-angle scale

  // lane-qubit product (qubits 4..9), packed over the 2 samples
  f32x2 lr, li;
  {
    float angA = enc[(size_t)sA*NQ + 4] * invr;
    float angB = enc[(size_t)sB*NQ + 4] * invr;
    f32x2 cv = {__cosf(angA), __cosf(angB)};
    f32x2 sv = {__sinf(angA), __sinf(angB)};
    float4 a = U0[8], b = U0[9];
    f32x2 pa_r = fma2(bc(a.z), sv, bc(a.x)*cv);
    f32x2 pa_i = fma2(bc(a.w), sv, bc(a.y)*cv);
    f32x2 pb_r = fma2(bc(b.z), sv, bc(b.x)*cv);
    f32x2 pb_i = fma2(bc(b.w), sv, bc(b.y)*cv);
    bool bit = lane & 1;
    lr = bit ? pb_r : pa_r;
    li = bit ? pb_i : pa_i;
  }
  #pragma unroll
  for (int j = 1; j < 6; ++j){
    int q = 4 + j;
    float angA = enc[(size_t)sA*NQ + q] * invr;
    float angB = enc[(size_t)sB*NQ + q] * invr;
    f32x2 cv = {__cosf(angA), __cosf(angB)};
    f32x2 sv = {__sinf(angA), __sinf(angB)};
    float4 a = U0[q*2+0], b = U0[q*2+1];
    f32x2 pa_r = fma2(bc(a.z), sv, bc(a.x)*cv);
    f32x2 pa_i = fma2(bc(a.w), sv, bc(a.y)*cv);
    f32x2 pb_r = fma2(bc(b.z), sv, bc(b.x)*cv);
    f32x2 pb_i = fma2(bc(b.w), sv, bc(b.y)*cv);
    bool bit = (lane >> j) & 1;
    f32x2 fr = bit ? pb_r : pa_r;
    f32x2 fi = bit ? pb_i : pa_i;
    f32x2 t = lr*fr - li*fi;
    li = fma2(lr, fi, li*fr);
    lr = t;
  }

  // register-qubit product tree (qubits 0..3)
  f32x2 re[16], im[16];
  re[0] = lr; im[0] = li;
  #pragma unroll
  for (int k = 0; k < 4; ++k){
    float angA = enc[(size_t)sA*NQ + k] * invr;
    float angB = enc[(size_t)sB*NQ + k] * invr;
    f32x2 cv = {__cosf(angA), __cosf(angB)};
    f32x2 sv = {__sinf(angA), __sinf(angB)};
    float4 a = U0[k*2+0], b = U0[k*2+1];
    f32x2 pa_r = fma2(bc(a.z), sv, bc(a.x)*cv);
    f32x2 pa_i = fma2(bc(a.w), sv, bc(a.y)*cv);
    f32x2 pb_r = fma2(bc(b.z), sv, bc(b.x)*cv);
    f32x2 pb_i = fma2(bc(b.w), sv, bc(b.y)*cv);
    int w = 1 << k;
    #pragma unroll
    for (int r = 0; r < 8; ++r) if (r < w){
      f32x2 xr = re[r], xi = im[r];
      re[r|w] = xr*pb_r - xi*pb_i;
      im[r|w] = fma2(xr, pb_i, xi*pb_r);
      re[r]   = xr*pa_r - xi*pa_i;
      im[r]   = fma2(xr, pa_i, xi*pa_r);
    }
  }

  run_layer<1>(re, im, gc2, phase4, lane);
  run_layer<2>(re, im, gc2, phase4, lane);
  run_layer<3>(re, im, gc2, phase4, lane);
  run_layer<4>(re, im, gc2, phase4, lane);
  run_layer<5>(re, im, gc2, phase4, lane);

  // probabilities -> 16-point WHT over register bits (packed)
  f32x2 p2[16];
  #pragma unroll
  for (int r = 0; r < 16; ++r) p2[r] = fma2(re[r], re[r], im[r]*im[r]);
  #pragma unroll
  for (int k = 0; k < 4; ++k){
    int w = 1 << k;
    #pragma unroll
    for (int r = 0; r < 16; ++r) if (!(r & w)){
      f32x2 a = p2[r], b = p2[r|w];
      p2[r] = a + b; p2[r|w] = a - b;
    }
  }
  // z_q partial = +/- p2[R&15], sign from lane bits; fuse FC
  f32x2 o2[4] = {{0.f,0.f},{0.f,0.f},{0.f,0.f},{0.f,0.f}};
  #pragma unroll
  for (int q = 0; q < NQ; ++q){
    constexpr int RALL[NQ] = {TAB.meas[0],TAB.meas[1],TAB.meas[2],TAB.meas[3],
                              TAB.meas[4],TAB.meas[5],TAB.meas[6],TAB.meas[7],
                              TAB.meas[8],TAB.meas[9]};
    int R = RALL[q];
    f32x2 tq = p2[R & 15];
    unsigned sg = (unsigned)(__popc((R >> 4) & lane) << 31);
    tq.x = __uint_as_float(__float_as_uint(tq.x) ^ sg);
    tq.y = __uint_as_float(__float_as_uint(tq.y) ^ sg);
    #pragma unroll
    for (int j = 0; j < 4; ++j) o2[j] = fma2(tq, bc(fcW[j*NQ + q]), o2[j]);
  }
  #pragma unroll
  for (int j = 0; j < 4; ++j){
    #pragma unroll
    for (int st = 1; st < 64; st <<= 1){
      o2[j].x += __shfl_xor(o2[j].x, st, 64);
      o2[j].y += __shfl_xor(o2[j].y, st, 64);
    }
  }
  if (lane == 0){
    float4 a4 = make_float4(o2[0].x+fcB[0], o2[1].x+fcB[1], o2[2].x+fcB[2], o2[3].x+fcB[3]);
    float4 b4 = make_float4(o2[0].y+fcB[0], o2[1].y+fcB[1], o2[2].y+fcB[2], o2[3].y+fcB[3]);
    *reinterpret_cast<float4*>(&outB[(size_t)sA*4]) = a4;
    *reinterpret_cast<float4*>(&outB[(size_t)sB*4]) = b4;
  }
}

// ---- K3: deterministic BN stats (single block) ----
__global__ __launch_bounds__(1024) void k3_stats(const float* __restrict__ outB,
                                                 float* __restrict__ stats)
{
  int tid = threadIdx.x;
  float sum[4] = {0,0,0,0}, sq[4] = {0,0,0,0};
  for (int row = tid; row < B_SZ; row += 1024){
    float4 v = *reinterpret_cast<const float4*>(outB + (size_t)row*4);
    sum[0]+=v.x; sq[0]+=v.x*v.x;
    sum[1]+=v.y; sq[1]+=v.y*v.y;
    sum[2]+=v.z; sq[2]+=v.z*v.z;
    sum[3]+=v.w; sq[3]+=v.w*v.w;
  }
  #pragma unroll
  for (int k = 0; k < 4; ++k){
    #pragma unroll
    for (int st = 1; st < 64; st <<= 1){
      sum[k] += __shfl_xor(sum[k], st, 64);
      sq[k]  += __shfl_xor(sq[k],  st, 64);
    }
  }
  __shared__ float ls[16][8];
  int lane = tid & 63, w = tid >> 6;
  if (lane == 0){
    #pragma unroll
    for (int k = 0; k < 4; ++k){ ls[w][k] = sum[k]; ls[w][4+k] = sq[k]; }
  }
  __syncthreads();
  if (tid == 0){
    float fs[8];
    #pragma unroll
    for (int k = 0; k < 8; ++k){
      float a = 0.f;
      for (int w2 = 0; w2 < 16; ++w2) a += ls[w2][k];
      fs[k] = a;
    }
    #pragma unroll
    for (int k = 0; k < 4; ++k){
      float mean = fs[k] * (1.f/B_SZ);
      float var  = fs[4+k] * (1.f/B_SZ) - mean*mean;
      stats[k]   = mean;
      stats[4+k] = rsqrtf(var + 1e-5f);
    }
  }
}

// ---- K4: apply BN ----
__global__ __launch_bounds__(256) void k4_bn(const float* __restrict__ outB,
    const float* __restrict__ stats, const float* __restrict__ gamma,
    const float* __restrict__ beta, float* __restrict__ out)
{
  int idx = blockIdx.x * 256 + threadIdx.x;
  int c = idx & 3;
  float v = outB[idx];
  out[idx] = gamma[c] * (v - stats[c]) * stats[4+c] + beta[c];
}

extern "C" void kernel_launch(void* const* d_in, const int* in_sizes, int n_in,
                              void* d_out, int out_size, void* d_ws, size_t ws_size,
                              hipStream_t stream)
{
  const float* x     = (const float*)d_in[0];
  const float* encW  = (const float*)d_in[1];
  const float* encB  = (const float*)d_in[2];
  const float* wts   = (const float*)d_in[3];
  const float* fcW   = (const float*)d_in[4];
  const float* fcB   = (const float*)d_in[5];
  const float* gamma = (const float*)d_in[6];
  const float* beta  = (const float*)d_in[7];

  char* ws = (char*)d_ws;
  unsigned* gkey  = (unsigned*)ws;                      // 4 B
  float4*  U0     = (float4*)(ws + 256);                // 320 B
  float2*  gc2    = (float2*)(ws + 1024);               // 400 B
  float4*  phase  = (float4*)(ws + 4096);               // 64 KB (c,c,s,s)
  float*   enc    = (float*)(ws + 4096 + 65536);
  float*   outB   = (float*)(ws + 4096 + 65536 + (size_t)B_SZ*NQ*4);
  float*   stats  = (float*)(ws + 4096 + 65536 + (size_t)B_SZ*NQ*4 + (size_t)B_SZ*4*4);

  hipLaunchKernelGGL(k_prep, dim3(16), dim3(256), 0, stream, wts, U0, gc2, phase, gkey);
  hipLaunchKernelGGL(k1_encode, dim3(B_SZ/256), dim3(256), 0, stream,
                     x, encW, encB, enc, gkey);
  hipLaunchKernelGGL(k2_qsim, dim3(B_SZ/8), dim3(256), 0, stream,
                     enc, gkey, U0, gc2, phase, fcW, fcB, outB);
  hipLaunchKernelGGL(k3_stats, dim3(1), dim3(1024), 0, stream, outB, stats);
  hipLaunchKernelGGL(k4_bn, dim3(B_SZ*4/256), dim3(256), 0, stream,
                     outB, stats, gamma, beta, (float*)d_out);
}

// Round 7
// 220.285 us; speedup vs baseline: 1.1400x; 1.1400x over previous
//
#include <hip/hip_runtime.h>
#include <math.h>

#define B_SZ 16384
#define NQ 10
#define DEPTH 6

typedef float f32x2 __attribute__((ext_vector_type(2)));

__device__ __forceinline__ f32x2 bc(float x){ return (f32x2){x, x}; }
__device__ __forceinline__ f32x2 fma2(f32x2 a, f32x2 b, f32x2 c){
  return __builtin_elementwise_fma(a, b, c);
}

// ---- constexpr GF(2) tracking of the CNOT ring ----
struct Tables {
  int m[DEPTH][NQ];   // phys xor-mask for gate on logical q at layer d
  int R[DEPTH][NQ];   // logical bit q of phys p = parity(R & p)
  int meas[NQ];       // final-basis rows for measurement
};
constexpr Tables make_tables(){
  Tables t{};
  int cols[NQ] = {}, rows[NQ] = {};
  for (int i = 0; i < NQ; ++i){ cols[i] = 1 << i; rows[i] = 1 << i; }
  for (int d = 0; d < DEPTH; ++d){
    for (int q = 0; q < NQ; ++q){ t.m[d][q] = cols[q]; t.R[d][q] = rows[q]; }
    for (int c = 0; c < NQ; ++c){          // ring: (0,1)..(8,9),(9,0)
      int tt = (c + 1) % NQ;
      cols[c]  ^= cols[tt];
      rows[tt] ^= rows[c];
    }
  }
  for (int q = 0; q < NQ; ++q) t.meas[q] = rows[q];
  return t;
}
constexpr Tables TAB = make_tables();

// ---- monotone float<->uint key for atomicMax over signed floats ----
__device__ __forceinline__ unsigned fkey(float x){
  unsigned b = __float_as_uint(x);
  return (b & 0x80000000u) ? ~b : (b | 0x80000000u);
}
__device__ __forceinline__ float funkey(unsigned k){
  unsigned b = (k & 0x80000000u) ? (k ^ 0x80000000u) : ~k;
  return __uint_as_float(b);
}

// ======== lane-xor exchange machinery ========
// Tiers (by confidence & cost):
//   lm<=15 : DPP only (quad_perm proven on HW R3/R4; mirror/half_mirror/ror8
//            encodings 0x140/0x141/0x128 per LLVM SIDefines)
//   16..31 : one ds_swizzle, bit-mode offset=(lm<<10)|0x1F (ISA-doc butterfly)
//   >=32   : permlane32_swap BUILTIN (SSA pair result -> no register aliasing)
//            with direction-independent partner extract r0^r1^x, then recurse.
constexpr int quadctl(int m){ return (0^m) | ((1^m)<<2) | ((2^m)<<4) | ((3^m)<<6); }

template<int CTRL>
__device__ __forceinline__ float dppf(float x){
  return __uint_as_float((unsigned)__builtin_amdgcn_update_dpp(
      0, (int)__float_as_uint(x), CTRL, 0xF, 0xF, true));
}
template<int LM>     // 1..31: xor within 32-lane halves, single DS op
__device__ __forceinline__ float dsswz(float x){
  return __uint_as_float((unsigned)__builtin_amdgcn_ds_swizzle(
      (int)__float_as_uint(x), (LM << 10) | 0x1F));
}
__device__ __forceinline__ float pl32(float x){
  unsigned u = __float_as_uint(x);
#if __has_builtin(__builtin_amdgcn_permlane32_swap)
  auto r = __builtin_amdgcn_permlane32_swap(u, u, false, false);
  // exactly one of r[0],r[1] is the lane's own value, the other is the
  // xor-32 partner (whichever swap direction HW uses) -> xor recovers partner
  return __uint_as_float(r[0] ^ r[1] ^ u);
#else
  return __shfl_xor(x, 32, 64);
#endif
}

template<int LM>
__device__ __forceinline__ float lxs(float x){
  if constexpr (LM == 0){
    return x;
  } else if constexpr (LM >= 32){
    return lxs<LM & 31>(pl32(x));
  } else if constexpr (LM >= 16){
    return dsswz<LM>(x);
  } else if constexpr (LM <= 3){
    return dppf<quadctl(LM)>(x);            // proven quad_perm
  } else if constexpr (LM == 7){
    return dppf<0x141>(x);                  // row_half_mirror: xor 7
  } else if constexpr (LM == 8){
    return dppf<0x128>(x);                  // row_ror:8 == xor 8
  } else if constexpr (LM == 15){
    return dppf<0x140>(x);                  // row_mirror: xor 15
  } else if constexpr ((LM & 12) == 4){
    return lxs<LM ^ 7>(dppf<0x141>(x));
  } else if constexpr ((LM & 12) == 8){
    return lxs<LM ^ 8>(dppf<0x128>(x));
  } else {
    return lxs<LM ^ 15>(dppf<0x140>(x));
  }
}
template<int LM>
__device__ __forceinline__ f32x2 lx2(f32x2 v){
  f32x2 r;
  r.x = lxs<LM>(v.x);
  r.y = lxs<LM>(v.y);
  return r;
}

// ---- prep: layer-0 fused 1q unitaries, Rx coeffs, diagonal phase tables ----
__global__ __launch_bounds__(256) void k_prep(const float* __restrict__ wts,
    float4* __restrict__ U0,     // 20: q*2+{0:(u00,u01),1:(u10,u11)}
    float2* __restrict__ gc2,    // 50: (d-1)*10+q -> (cos ax, sin ax)
    float4* __restrict__ phase,  // 4*1024: layers 1..4 diagonal (c,c,s,s)
    unsigned* __restrict__ gkey)
{
  int idx = blockIdx.x * 256 + threadIdx.x;
  if (idx < 4096){
    int layer = 1 + (idx >> 10);
    int p = idx & 1023;
    float phi = 0.f;
    for (int q = 0; q < NQ; ++q){
      float az = wts[(layer*NQ + q)*2 + 1] * 0.5f;
      phi += (__popc(TAB.R[layer][q] & p) & 1) ? az : -az;
    }
    float c = cosf(phi), s = sinf(phi);
    phase[idx] = make_float4(c, c, s, s);
  }
  if (blockIdx.x == 0){
    int t = threadIdx.x;
    if (t < NQ){
      float ax = wts[t*2+0]*0.5f, az = wts[t*2+1]*0.5f;
      float ca=cosf(ax), sa=sinf(ax), cz=cosf(az), sz=sinf(az);
      U0[t*2+0] = make_float4(ca*cz, -ca*sz, -sa*sz, -sa*cz); // u00r,u00i,u01r,u01i
      U0[t*2+1] = make_float4(sa*sz, -sa*cz,  ca*cz,  ca*sz); // u10r,u10i,u11r,u11i
    } else if (t >= 64 && t < 64 + 50){
      int g = t - 64;                     // (d-1)*10+q, d=1..5
      int d = 1 + g/10, q = g - (d-1)*10;
      float ax = wts[(d*NQ+q)*2+0]*0.5f;
      gc2[g] = make_float2(cosf(ax), sinf(ax));
    } else if (t == 120){
      *gkey = 0u;
    }
  }
}

// ---- K1: pool -> encode -> global max ----
__global__ __launch_bounds__(256) void k1_encode(const float* __restrict__ x,
    const float* __restrict__ encW, const float* __restrict__ encB,
    float* __restrict__ encOut, unsigned* __restrict__ gkey)
{
  int s = blockIdx.x * 256 + threadIdx.x;
  const float* xs = x + (size_t)s * 784;
  float pool[16];
  #pragma unroll
  for (int i = 0; i < 16; ++i) pool[i] = 0.f;
  #pragma unroll
  for (int row = 0; row < 24; ++row){
    int p = row / 6;
    #pragma unroll
    for (int c4 = 0; c4 < 6; ++c4){
      float4 v = *reinterpret_cast<const float4*>(xs + row * 28 + c4 * 4);
      int c0 = c4 * 4;
      pool[p*4 + (c0+0)/6] += v.x;
      pool[p*4 + (c0+1)/6] += v.y;
      pool[p*4 + (c0+2)/6] += v.z;
      pool[p*4 + (c0+3)/6] += v.w;
    }
  }
  #pragma unroll
  for (int i = 0; i < 16; ++i) pool[i] *= (1.f/36.f);

  float m = -INFINITY;
  #pragma unroll
  for (int i = 0; i < NQ; ++i){
    float e = encB[i];
    #pragma unroll
    for (int k = 0; k < 16; ++k) e = fmaf(pool[k], encW[i*16+k], e);
    encOut[(size_t)s*NQ + i] = e;
    m = fmaxf(m, e);
  }
  #pragma unroll
  for (int st = 1; st < 64; st <<= 1) m = fmaxf(m, __shfl_xor(m, st, 64));
  __shared__ float wm[4];
  int lane = threadIdx.x & 63, w = threadIdx.x >> 6;
  if (lane == 0) wm[w] = m;
  __syncthreads();
  if (threadIdx.x == 0){
    float mm = fmaxf(fmaxf(wm[0], wm[1]), fmaxf(wm[2], wm[3]));
    atomicMax(gkey, fkey(mm));
  }
}

// ---- Rx gate on packed 2-sample state ----
template<int D, int Q>
__device__ __forceinline__ void rx_gate(f32x2 (&re)[16], f32x2 (&im)[16],
    const float2* __restrict__ gc2)
{
  constexpr int m  = TAB.m[D][Q];
  constexpr int rm = m & 15;
  constexpr int lm = m >> 4;
  float2 c = gc2[(D-1)*NQ + Q];     // wave-uniform -> s_load
  f32x2 ca = bc(c.x), sa = bc(c.y);
  f32x2 nsa = -sa;

  if constexpr (lm == 0){
    constexpr int lb = rm & (-rm);
    #pragma unroll
    for (int r = 0; r < 16; ++r) if (!(r & lb)){
      int r2 = r ^ rm;
      f32x2 ar = re[r],  ai = im[r];
      f32x2 br = re[r2], bi = im[r2];
      re[r]  = fma2(sa,  bi, ca*ar);
      im[r]  = fma2(nsa, br, ca*ai);
      re[r2] = fma2(sa,  ai, ca*br);
      im[r2] = fma2(nsa, ar, ca*bi);
    }
  } else if constexpr (rm == 0){
    #pragma unroll
    for (int r = 0; r < 16; ++r){
      f32x2 bi = lx2<lm>(im[r]);
      f32x2 br = lx2<lm>(re[r]);
      re[r] = fma2(sa,  bi, ca*re[r]);
      im[r] = fma2(nsa, br, ca*im[r]);
    }
  } else {
    constexpr int lb = rm & (-rm);
    #pragma unroll
    for (int r = 0; r < 16; ++r) if (!(r & lb)){
      int r2 = r ^ rm;
      f32x2 bi2 = lx2<lm>(im[r2]);
      f32x2 br2 = lx2<lm>(re[r2]);
      f32x2 bi1 = lx2<lm>(im[r]);
      f32x2 br1 = lx2<lm>(re[r]);
      re[r]  = fma2(sa,  bi2, ca*re[r]);
      im[r]  = fma2(nsa, br2, ca*im[r]);
      re[r2] = fma2(sa,  bi1, ca*re[r2]);
      im[r2] = fma2(nsa, br1, ca*im[r2]);
    }
  }
}

template<int D>
__device__ __forceinline__ void run_layer(f32x2 (&re)[16], f32x2 (&im)[16],
    const float2* __restrict__ gc2, const float4* __restrict__ phase4, int lane)
{
  rx_gate<D,0>(re, im, gc2);
  rx_gate<D,1>(re, im, gc2);
  rx_gate<D,2>(re, im, gc2);
  rx_gate<D,3>(re, im, gc2);
  rx_gate<D,4>(re, im, gc2);
  rx_gate<D,5>(re, im, gc2);
  rx_gate<D,6>(re, im, gc2);
  rx_gate<D,7>(re, im, gc2);
  rx_gate<D,8>(re, im, gc2);
  rx_gate<D,9>(re, im, gc2);
  if constexpr (D <= 4){
    const float4* __restrict__ pp = phase4 + (size_t)(D-1)*1024 + lane*16;
    #pragma unroll
    for (int r = 0; r < 16; ++r){
      float4 ph = pp[r];
      f32x2 cp = {ph.x, ph.y};
      f32x2 sp = {ph.z, ph.w};
      f32x2 ar = re[r], ai = im[r];
      re[r] = fma2(-sp, ai, cp*ar);
      im[r] = fma2( sp, ar, cp*ai);
    }
  }
  // D == 5: final diagonal dropped — phases don't affect |amp|^2
}

// ---- K2: one wave per TWO samples (packed in f32x2 components) ----
// amp index: bits[3:0] = register index, bits[9:4] = lane
__global__ __launch_bounds__(256) void k2_qsim(
    const float* __restrict__ enc, const unsigned* __restrict__ gkey,
    const float4* __restrict__ U0, const float2* __restrict__ gc2,
    const float4* __restrict__ phase4,
    const float* __restrict__ fcW, const float* __restrict__ fcB,
    float* __restrict__ outB)
{
  int tid  = threadIdx.x;
  int lane = tid & 63;
  int wid  = tid >> 6;
  int sA   = blockIdx.x * 8 + wid * 2;
  int sB   = sA + 1;

  float invr = 3.14159265358979f / (funkey(*gkey) + 1e-8f); // half-angle scale

  // lane-qubit product (qubits 4..9), packed over the 2 samples
  f32x2 lr, li;
  {
    float angA = enc[(size_t)sA*NQ + 4] * invr;
    float angB = enc[(size_t)sB*NQ + 4] * invr;
    f32x2 cv = {__cosf(angA), __cosf(angB)};
    f32x2 sv = {__sinf(angA), __sinf(angB)};
    float4 a = U0[8], b = U0[9];
    f32x2 pa_r = fma2(bc(a.z), sv, bc(a.x)*cv);
    f32x2 pa_i = fma2(bc(a.w), sv, bc(a.y)*cv);
    f32x2 pb_r = fma2(bc(b.z), sv, bc(b.x)*cv);
    f32x2 pb_i = fma2(bc(b.w), sv, bc(b.y)*cv);
    bool bit = lane & 1;
    lr = bit ? pb_r : pa_r;
    li = bit ? pb_i : pa_i;
  }
  #pragma unroll
  for (int j = 1; j < 6; ++j){
    int q = 4 + j;
    float angA = enc[(size_t)sA*NQ + q] * invr;
    float angB = enc[(size_t)sB*NQ + q] * invr;
    f32x2 cv = {__cosf(angA), __cosf(angB)};
    f32x2 sv = {__sinf(angA), __sinf(angB)};
    float4 a = U0[q*2+0], b = U0[q*2+1];
    f32x2 pa_r = fma2(bc(a.z), sv, bc(a.x)*cv);
    f32x2 pa_i = fma2(bc(a.w), sv, bc(a.y)*cv);
    f32x2 pb_r = fma2(bc(b.z), sv, bc(b.x)*cv);
    f32x2 pb_i = fma2(bc(b.w), sv, bc(b.y)*cv);
    bool bit = (lane >> j) & 1;
    f32x2 fr = bit ? pb_r : pa_r;
    f32x2 fi = bit ? pb_i : pa_i;
    f32x2 t = lr*fr - li*fi;
    li = fma2(lr, fi, li*fr);
    lr = t;
  }

  // register-qubit product tree (qubits 0..3)
  f32x2 re[16], im[16];
  re[0] = lr; im[0] = li;
  #pragma unroll
  for (int k = 0; k < 4; ++k){
    float angA = enc[(size_t)sA*NQ + k] * invr;
    float angB = enc[(size_t)sB*NQ + k] * invr;
    f32x2 cv = {__cosf(angA), __cosf(angB)};
    f32x2 sv = {__sinf(angA), __sinf(angB)};
    float4 a = U0[k*2+0], b = U0[k*2+1];
    f32x2 pa_r = fma2(bc(a.z), sv, bc(a.x)*cv);
    f32x2 pa_i = fma2(bc(a.w), sv, bc(a.y)*cv);
    f32x2 pb_r = fma2(bc(b.z), sv, bc(b.x)*cv);
    f32x2 pb_i = fma2(bc(b.w), sv, bc(b.y)*cv);
    int w = 1 << k;
    #pragma unroll
    for (int r = 0; r < 8; ++r) if (r < w){
      f32x2 xr = re[r], xi = im[r];
      re[r|w] = xr*pb_r - xi*pb_i;
      im[r|w] = fma2(xr, pb_i, xi*pb_r);
      re[r]   = xr*pa_r - xi*pa_i;
      im[r]   = fma2(xr, pa_i, xi*pa_r);
    }
  }

  run_layer<1>(re, im, gc2, phase4, lane);
  run_layer<2>(re, im, gc2, phase4, lane);
  run_layer<3>(re, im, gc2, phase4, lane);
  run_layer<4>(re, im, gc2, phase4, lane);
  run_layer<5>(re, im, gc2, phase4, lane);

  // probabilities -> 16-point WHT over register bits (packed)
  f32x2 p2[16];
  #pragma unroll
  for (int r = 0; r < 16; ++r) p2[r] = fma2(re[r], re[r], im[r]*im[r]);
  #pragma unroll
  for (int k = 0; k < 4; ++k){
    int w = 1 << k;
    #pragma unroll
    for (int r = 0; r < 16; ++r) if (!(r & w)){
      f32x2 a = p2[r], b = p2[r|w];
      p2[r] = a + b; p2[r|w] = a - b;
    }
  }
  // z_q partial = +/- p2[R&15], sign from lane bits; fuse FC
  f32x2 o2[4] = {{0.f,0.f},{0.f,0.f},{0.f,0.f},{0.f,0.f}};
  #pragma unroll
  for (int q = 0; q < NQ; ++q){
    constexpr int RALL[NQ] = {TAB.meas[0],TAB.meas[1],TAB.meas[2],TAB.meas[3],
                              TAB.meas[4],TAB.meas[5],TAB.meas[6],TAB.meas[7],
                              TAB.meas[8],TAB.meas[9]};
    int R = RALL[q];
    f32x2 tq = p2[R & 15];
    unsigned sg = (unsigned)(__popc((R >> 4) & lane) << 31);
    tq.x = __uint_as_float(__float_as_uint(tq.x) ^ sg);
    tq.y = __uint_as_float(__float_as_uint(tq.y) ^ sg);
    #pragma unroll
    for (int j = 0; j < 4; ++j) o2[j] = fma2(tq, bc(fcW[j*NQ + q]), o2[j]);
  }
  // butterfly reduce (DPP for 1..8, one swizzle for 16, permlane for 32)
  #pragma unroll
  for (int j = 0; j < 4; ++j){
    o2[j].x += lxs<1>(o2[j].x);   o2[j].y += lxs<1>(o2[j].y);
    o2[j].x += lxs<2>(o2[j].x);   o2[j].y += lxs<2>(o2[j].y);
    o2[j].x += lxs<4>(o2[j].x);   o2[j].y += lxs<4>(o2[j].y);
    o2[j].x += lxs<8>(o2[j].x);   o2[j].y += lxs<8>(o2[j].y);
    o2[j].x += lxs<16>(o2[j].x);  o2[j].y += lxs<16>(o2[j].y);
    o2[j].x += lxs<32>(o2[j].x);  o2[j].y += lxs<32>(o2[j].y);
  }
  if (lane == 0){
    float4 a4 = make_float4(o2[0].x+fcB[0], o2[1].x+fcB[1], o2[2].x+fcB[2], o2[3].x+fcB[3]);
    float4 b4 = make_float4(o2[0].y+fcB[0], o2[1].y+fcB[1], o2[2].y+fcB[2], o2[3].y+fcB[3]);
    *reinterpret_cast<float4*>(&outB[(size_t)sA*4]) = a4;
    *reinterpret_cast<float4*>(&outB[(size_t)sB*4]) = b4;
  }
}

// ---- K3: deterministic BN stats (single block) ----
__global__ __launch_bounds__(1024) void k3_stats(const float* __restrict__ outB,
                                                 float* __restrict__ stats)
{
  int tid = threadIdx.x;
  float sum[4] = {0,0,0,0}, sq[4] = {0,0,0,0};
  for (int row = tid; row < B_SZ; row += 1024){
    float4 v = *reinterpret_cast<const float4*>(outB + (size_t)row*4);
    sum[0]+=v.x; sq[0]+=v.x*v.x;
    sum[1]+=v.y; sq[1]+=v.y*v.y;
    sum[2]+=v.z; sq[2]+=v.z*v.z;
    sum[3]+=v.w; sq[3]+=v.w*v.w;
  }
  #pragma unroll
  for (int k = 0; k < 4; ++k){
    #pragma unroll
    for (int st = 1; st < 64; st <<= 1){
      sum[k] += __shfl_xor(sum[k], st, 64);
      sq[k]  += __shfl_xor(sq[k],  st, 64);
    }
  }
  __shared__ float ls[16][8];
  int lane = tid & 63, w = tid >> 6;
  if (lane == 0){
    #pragma unroll
    for (int k = 0; k < 4; ++k){ ls[w][k] = sum[k]; ls[w][4+k] = sq[k]; }
  }
  __syncthreads();
  if (tid == 0){
    float fs[8];
    #pragma unroll
    for (int k = 0; k < 8; ++k){
      float a = 0.f;
      for (int w2 = 0; w2 < 16; ++w2) a += ls[w2][k];
      fs[k] = a;
    }
    #pragma unroll
    for (int k = 0; k < 4; ++k){
      float mean = fs[k] * (1.f/B_SZ);
      float var  = fs[4+k] * (1.f/B_SZ) - mean*mean;
      stats[k]   = mean;
      stats[4+k] = rsqrtf(var + 1e-5f);
    }
  }
}

// ---- K4: apply BN ----
__global__ __launch_bounds__(256) void k4_bn(const float* __restrict__ outB,
    const float* __restrict__ stats, const float* __restrict__ gamma,
    const float* __restrict__ beta, float* __restrict__ out)
{
  int idx = blockIdx.x * 256 + threadIdx.x;
  int c = idx & 3;
  float v = outB[idx];
  out[idx] = gamma[c] * (v - stats[c]) * stats[4+c] + beta[c];
}

extern "C" void kernel_launch(void* const* d_in, const int* in_sizes, int n_in,
                              void* d_out, int out_size, void* d_ws, size_t ws_size,
                              hipStream_t stream)
{
  const float* x     = (const float*)d_in[0];
  const float* encW  = (const float*)d_in[1];
  const float* encB  = (const float*)d_in[2];
  const float* wts   = (const float*)d_in[3];
  const float* fcW   = (const float*)d_in[4];
  const float* fcB   = (const float*)d_in[5];
  const float* gamma = (const float*)d_in[6];
  const float* beta  = (const float*)d_in[7];

  char* ws = (char*)d_ws;
  unsigned* gkey  = (unsigned*)ws;                      // 4 B
  float4*  U0     = (float4*)(ws + 256);                // 320 B
  float2*  gc2    = (float2*)(ws + 1024);               // 400 B
  float4*  phase  = (float4*)(ws + 4096);               // 64 KB (c,c,s,s)
  float*   enc    = (float*)(ws + 4096 + 65536);
  float*   outB   = (float*)(ws + 4096 + 65536 + (size_t)B_SZ*NQ*4);
  float*   stats  = (float*)(ws + 4096 + 65536 + (size_t)B_SZ*NQ*4 + (size_t)B_SZ*4*4);

  hipLaunchKernelGGL(k_prep, dim3(16), dim3(256), 0, stream, wts, U0, gc2, phase, gkey);
  hipLaunchKernelGGL(k1_encode, dim3(B_SZ/256), dim3(256), 0, stream,
                     x, encW, encB, enc, gkey);
  hipLaunchKernelGGL(k2_qsim, dim3(B_SZ/8), dim3(256), 0, stream,
                     enc, gkey, U0, gc2, phase, fcW, fcB, outB);
  hipLaunchKernelGGL(k3_stats, dim3(1), dim3(1024), 0, stream, outB, stats);
  hipLaunchKernelGGL(k4_bn, dim3(B_SZ*4/256), dim3(256), 0, stream,
                     outB, stats, gamma, beta, (float*)d_out);
}

// Round 8
// 201.578 us; speedup vs baseline: 1.2457x; 1.0928x over previous
//
#include <hip/hip_runtime.h>
#include <math.h>

#define B_SZ 16384
#define NQ 10
#define DEPTH 6

typedef float f32x2 __attribute__((ext_vector_type(2)));

__device__ __forceinline__ f32x2 bc(float x){ return (f32x2){x, x}; }
__device__ __forceinline__ f32x2 fma2(f32x2 a, f32x2 b, f32x2 c){
  return __builtin_elementwise_fma(a, b, c);
}

// ---- constexpr GF(2) tracking of the CNOT ring ----
struct Tables {
  int m[DEPTH][NQ];   // phys xor-mask for gate on logical q at layer d
  int R[DEPTH][NQ];   // logical bit q of phys p = parity(R & p)
  int meas[NQ];       // final-basis rows for measurement
};
constexpr Tables make_tables(){
  Tables t{};
  int cols[NQ] = {}, rows[NQ] = {};
  for (int i = 0; i < NQ; ++i){ cols[i] = 1 << i; rows[i] = 1 << i; }
  for (int d = 0; d < DEPTH; ++d){
    for (int q = 0; q < NQ; ++q){ t.m[d][q] = cols[q]; t.R[d][q] = rows[q]; }
    for (int c = 0; c < NQ; ++c){          // ring: (0,1)..(8,9),(9,0)
      int tt = (c + 1) % NQ;
      cols[c]  ^= cols[tt];
      rows[tt] ^= rows[c];
    }
  }
  for (int q = 0; q < NQ; ++q) t.meas[q] = rows[q];
  return t;
}
constexpr Tables TAB = make_tables();

// ---- monotone float<->uint key for atomicMax over signed floats ----
__device__ __forceinline__ unsigned fkey(float x){
  unsigned b = __float_as_uint(x);
  return (b & 0x80000000u) ? ~b : (b | 0x80000000u);
}
__device__ __forceinline__ float funkey(unsigned k){
  unsigned b = (k & 0x80000000u) ? (k ^ 0x80000000u) : ~k;
  return __uint_as_float(b);
}

// ======== lane-xor exchange machinery (proven in R7) ========
constexpr int quadctl(int m){ return (0^m) | ((1^m)<<2) | ((2^m)<<4) | ((3^m)<<6); }

template<int CTRL>
__device__ __forceinline__ float dppf(float x){
  return __uint_as_float((unsigned)__builtin_amdgcn_update_dpp(
      0, (int)__float_as_uint(x), CTRL, 0xF, 0xF, true));
}
template<int LM>     // 1..31: xor within 32-lane halves, single DS op
__device__ __forceinline__ float dsswz(float x){
  return __uint_as_float((unsigned)__builtin_amdgcn_ds_swizzle(
      (int)__float_as_uint(x), (LM << 10) | 0x1F));
}
__device__ __forceinline__ float pl32(float x){
  unsigned u = __float_as_uint(x);
#if __has_builtin(__builtin_amdgcn_permlane32_swap)
  auto r = __builtin_amdgcn_permlane32_swap(u, u, false, false);
  return __uint_as_float(r[0] ^ r[1] ^ u);   // direction-independent partner
#else
  return __shfl_xor(x, 32, 64);
#endif
}

template<int LM>
__device__ __forceinline__ float lxs(float x){
  if constexpr (LM == 0){
    return x;
  } else if constexpr (LM >= 32){
    return lxs<LM & 31>(pl32(x));
  } else if constexpr (LM >= 16){
    return dsswz<LM>(x);
  } else if constexpr (LM <= 3){
    return dppf<quadctl(LM)>(x);            // quad_perm xor 1..3
  } else if constexpr (LM == 7){
    return dppf<0x141>(x);                  // row_half_mirror: xor 7
  } else if constexpr (LM == 8){
    return dppf<0x128>(x);                  // row_ror:8 == xor 8
  } else if constexpr (LM == 15){
    return dppf<0x140>(x);                  // row_mirror: xor 15
  } else if constexpr ((LM & 12) == 4){
    return lxs<LM ^ 7>(dppf<0x141>(x));
  } else if constexpr ((LM & 12) == 8){
    return lxs<LM ^ 8>(dppf<0x128>(x));
  } else {
    return lxs<LM ^ 15>(dppf<0x140>(x));
  }
}
template<int LM>
__device__ __forceinline__ f32x2 lx2(f32x2 v){
  f32x2 r;
  r.x = lxs<LM>(v.x);
  r.y = lxs<LM>(v.y);
  return r;
}

// ---- prep: U0, per-gate tangents, deferred-cos scaled FC weights, phases ----
__global__ __launch_bounds__(256) void k_prep(const float* __restrict__ wts,
    const float* __restrict__ fcW,
    float4* __restrict__ U0,     // 20: q*2+{0:(u00,u01),1:(u10,u11)}
    float* __restrict__ gcT,     // 50: (d-1)*10+q -> tan(ax)
    float4* __restrict__ phase,  // 4*1024: layers 1..4 diagonal (c,c,s,s)
    float* __restrict__ fcWs,    // 40: fcW * (prod cos)^2
    unsigned* __restrict__ gkey)
{
  int idx = blockIdx.x * 256 + threadIdx.x;
  if (idx < 4096){
    int layer = 1 + (idx >> 10);
    int p = idx & 1023;
    float phi = 0.f;
    for (int q = 0; q < NQ; ++q){
      float az = wts[(layer*NQ + q)*2 + 1] * 0.5f;
      phi += (__popc(TAB.R[layer][q] & p) & 1) ? az : -az;
    }
    float c = cosf(phi), s = sinf(phi);
    phase[idx] = make_float4(c, c, s, s);
  }
  if (blockIdx.x == 0){
    int t = threadIdx.x;
    if (t < NQ){
      float ax = wts[t*2+0]*0.5f, az = wts[t*2+1]*0.5f;
      float ca=cosf(ax), sa=sinf(ax), cz=cosf(az), sz=sinf(az);
      U0[t*2+0] = make_float4(ca*cz, -ca*sz, -sa*sz, -sa*cz); // u00r,u00i,u01r,u01i
      U0[t*2+1] = make_float4(sa*sz, -sa*cz,  ca*cz,  ca*sz); // u10r,u10i,u11r,u11i
    } else if (t >= 64 && t < 64 + 50){
      int g = t - 64;                     // (d-1)*10+q, d=1..5
      int d = 1 + g/10, q = g % 10;
      float ax = wts[(d*NQ+q)*2+0]*0.5f;
      gcT[g] = tanf(ax);
    } else if (t == 120){
      *gkey = 0u;
    } else if (t == 121){
      float pc = 1.f;
      for (int g = 0; g < 50; ++g){
        int d = 1 + g/10, q = g % 10;
        pc *= cosf(wts[(d*NQ+q)*2+0]*0.5f);
      }
      float s2 = pc * pc;
      for (int j = 0; j < 40; ++j) fcWs[j] = fcW[j] * s2;
    }
  }
}

// ---- K1: pool -> encode -> global max ----
__global__ __launch_bounds__(256) void k1_encode(const float* __restrict__ x,
    const float* __restrict__ encW, const float* __restrict__ encB,
    float* __restrict__ encOut, unsigned* __restrict__ gkey)
{
  int s = blockIdx.x * 256 + threadIdx.x;
  const float* xs = x + (size_t)s * 784;
  float pool[16];
  #pragma unroll
  for (int i = 0; i < 16; ++i) pool[i] = 0.f;
  #pragma unroll
  for (int row = 0; row < 24; ++row){
    int p = row / 6;
    #pragma unroll
    for (int c4 = 0; c4 < 6; ++c4){
      float4 v = *reinterpret_cast<const float4*>(xs + row * 28 + c4 * 4);
      int c0 = c4 * 4;
      pool[p*4 + (c0+0)/6] += v.x;
      pool[p*4 + (c0+1)/6] += v.y;
      pool[p*4 + (c0+2)/6] += v.z;
      pool[p*4 + (c0+3)/6] += v.w;
    }
  }
  #pragma unroll
  for (int i = 0; i < 16; ++i) pool[i] *= (1.f/36.f);

  float m = -INFINITY;
  #pragma unroll
  for (int i = 0; i < NQ; ++i){
    float e = encB[i];
    #pragma unroll
    for (int k = 0; k < 16; ++k) e = fmaf(pool[k], encW[i*16+k], e);
    encOut[(size_t)s*NQ + i] = e;
    m = fmaxf(m, e);
  }
  #pragma unroll
  for (int st = 1; st < 64; st <<= 1) m = fmaxf(m, __shfl_xor(m, st, 64));
  __shared__ float wm[4];
  int lane = threadIdx.x & 63, w = threadIdx.x >> 6;
  if (lane == 0) wm[w] = m;
  __syncthreads();
  if (threadIdx.x == 0){
    float mm = fmaxf(fmaxf(wm[0], wm[1]), fmaxf(wm[2], wm[3]));
    atomicMax(gkey, fkey(mm));
  }
}

// ---- Rx gate, tangent form (cos deferred into fcWs): 1 FMA per output ----
template<int D, int Q>
__device__ __forceinline__ void rx_gate(f32x2 (&re)[16], f32x2 (&im)[16],
    const float* __restrict__ gcT)
{
  constexpr int m  = TAB.m[D][Q];
  constexpr int rm = m & 15;
  constexpr int lm = m >> 4;
  float Tt = gcT[(D-1)*NQ + Q];     // wave-uniform
  f32x2 T = bc(Tt), nT = bc(-Tt);

  if constexpr (lm == 0){
    constexpr int lb = rm & (-rm);
    #pragma unroll
    for (int r = 0; r < 16; ++r) if (!(r & lb)){
      int r2 = r ^ rm;
      f32x2 ar = re[r],  ai = im[r];
      f32x2 br = re[r2], bi = im[r2];
      re[r]  = fma2(T,  bi, ar);
      im[r]  = fma2(nT, br, ai);
      re[r2] = fma2(T,  ai, br);
      im[r2] = fma2(nT, ar, bi);
    }
  } else if constexpr (rm == 0){
    #pragma unroll
    for (int r = 0; r < 16; ++r){
      f32x2 bi = lx2<lm>(im[r]);
      f32x2 br = lx2<lm>(re[r]);
      re[r] = fma2(T,  bi, re[r]);
      im[r] = fma2(nT, br, im[r]);
    }
  } else {
    constexpr int lb = rm & (-rm);
    #pragma unroll
    for (int r = 0; r < 16; ++r) if (!(r & lb)){
      int r2 = r ^ rm;
      f32x2 bi2 = lx2<lm>(im[r2]);
      f32x2 br2 = lx2<lm>(re[r2]);
      f32x2 bi1 = lx2<lm>(im[r]);
      f32x2 br1 = lx2<lm>(re[r]);
      re[r]  = fma2(T,  bi2, re[r]);
      im[r]  = fma2(nT, br2, im[r]);
      re[r2] = fma2(T,  bi1, re[r2]);
      im[r2] = fma2(nT, br1, im[r2]);
    }
  }
}

template<int D>
__device__ __forceinline__ void run_layer(f32x2 (&re)[16], f32x2 (&im)[16],
    const float* __restrict__ gcT, const float4* __restrict__ phase4, int lane)
{
  rx_gate<D,0>(re, im, gcT);
  rx_gate<D,1>(re, im, gcT);
  rx_gate<D,2>(re, im, gcT);
  rx_gate<D,3>(re, im, gcT);
  rx_gate<D,4>(re, im, gcT);
  rx_gate<D,5>(re, im, gcT);
  rx_gate<D,6>(re, im, gcT);
  rx_gate<D,7>(re, im, gcT);
  rx_gate<D,8>(re, im, gcT);
  rx_gate<D,9>(re, im, gcT);
  if constexpr (D <= 4){
    const float4* __restrict__ pp = phase4 + (size_t)(D-1)*1024 + lane*16;
    #pragma unroll
    for (int r = 0; r < 16; ++r){
      float4 ph = pp[r];
      f32x2 cp = {ph.x, ph.y};
      f32x2 sp = {ph.z, ph.w};
      f32x2 ar = re[r], ai = im[r];
      re[r] = fma2(-sp, ai, cp*ar);
      im[r] = fma2( sp, ar, cp*ai);
    }
  }
  // D == 5: final diagonal dropped — phases don't affect |amp|^2
}

// ---- K2: one wave per TWO samples (packed in f32x2 components) ----
// amp index: bits[3:0] = register index, bits[9:4] = lane
__global__ __launch_bounds__(256) void k2_qsim(
    const float* __restrict__ enc, const unsigned* __restrict__ gkey,
    const float4* __restrict__ U0, const float* __restrict__ gcT,
    const float4* __restrict__ phase4,
    const float* __restrict__ fcWs, const float* __restrict__ fcB,
    float* __restrict__ outB)
{
  int tid  = threadIdx.x;
  int lane = tid & 63;
  int wid  = tid >> 6;
  int sA   = blockIdx.x * 8 + wid * 2;
  int sB   = sA + 1;

  float invr = 3.14159265358979f / (funkey(*gkey) + 1e-8f); // half-angle scale

  // lane-qubit product (qubits 4..9), packed over the 2 samples
  f32x2 lr, li;
  {
    float angA = enc[(size_t)sA*NQ + 4] * invr;
    float angB = enc[(size_t)sB*NQ + 4] * invr;
    f32x2 cv = {__cosf(angA), __cosf(angB)};
    f32x2 sv = {__sinf(angA), __sinf(angB)};
    float4 a = U0[8], b = U0[9];
    f32x2 pa_r = fma2(bc(a.z), sv, bc(a.x)*cv);
    f32x2 pa_i = fma2(bc(a.w), sv, bc(a.y)*cv);
    f32x2 pb_r = fma2(bc(b.z), sv, bc(b.x)*cv);
    f32x2 pb_i = fma2(bc(b.w), sv, bc(b.y)*cv);
    bool bit = lane & 1;
    lr = bit ? pb_r : pa_r;
    li = bit ? pb_i : pa_i;
  }
  #pragma unroll
  for (int j = 1; j < 6; ++j){
    int q = 4 + j;
    float angA = enc[(size_t)sA*NQ + q] * invr;
    float angB = enc[(size_t)sB*NQ + q] * invr;
    f32x2 cv = {__cosf(angA), __cosf(angB)};
    f32x2 sv = {__sinf(angA), __sinf(angB)};
    float4 a = U0[q*2+0], b = U0[q*2+1];
    f32x2 pa_r = fma2(bc(a.z), sv, bc(a.x)*cv);
    f32x2 pa_i = fma2(bc(a.w), sv, bc(a.y)*cv);
    f32x2 pb_r = fma2(bc(b.z), sv, bc(b.x)*cv);
    f32x2 pb_i = fma2(bc(b.w), sv, bc(b.y)*cv);
    bool bit = (lane >> j) & 1;
    f32x2 fr = bit ? pb_r : pa_r;
    f32x2 fi = bit ? pb_i : pa_i;
    f32x2 t = lr*fr - li*fi;
    li = fma2(lr, fi, li*fr);
    lr = t;
  }

  // register-qubit product tree (qubits 0..3)
  f32x2 re[16], im[16];
  re[0] = lr; im[0] = li;
  #pragma unroll
  for (int k = 0; k < 4; ++k){
    float angA = enc[(size_t)sA*NQ + k] * invr;
    float angB = enc[(size_t)sB*NQ + k] * invr;
    f32x2 cv = {__cosf(angA), __cosf(angB)};
    f32x2 sv = {__sinf(angA), __sinf(angB)};
    float4 a = U0[k*2+0], b = U0[k*2+1];
    f32x2 pa_r = fma2(bc(a.z), sv, bc(a.x)*cv);
    f32x2 pa_i = fma2(bc(a.w), sv, bc(a.y)*cv);
    f32x2 pb_r = fma2(bc(b.z), sv, bc(b.x)*cv);
    f32x2 pb_i = fma2(bc(b.w), sv, bc(b.y)*cv);
    int w = 1 << k;
    #pragma unroll
    for (int r = 0; r < 8; ++r) if (r < w){
      f32x2 xr = re[r], xi = im[r];
      re[r|w] = xr*pb_r - xi*pb_i;
      im[r|w] = fma2(xr, pb_i, xi*pb_r);
      re[r]   = xr*pa_r - xi*pa_i;
      im[r]   = fma2(xr, pa_i, xi*pa_r);
    }
  }

  run_layer<1>(re, im, gcT, phase4, lane);
  run_layer<2>(re, im, gcT, phase4, lane);
  run_layer<3>(re, im, gcT, phase4, lane);
  run_layer<4>(re, im, gcT, phase4, lane);
  run_layer<5>(re, im, gcT, phase4, lane);

  // probabilities -> 16-point WHT over register bits (packed)
  f32x2 p2[16];
  #pragma unroll
  for (int r = 0; r < 16; ++r) p2[r] = fma2(re[r], re[r], im[r]*im[r]);
  #pragma unroll
  for (int k = 0; k < 4; ++k){
    int w = 1 << k;
    #pragma unroll
    for (int r = 0; r < 16; ++r) if (!(r & w)){
      f32x2 a = p2[r], b = p2[r|w];
      p2[r] = a + b; p2[r|w] = a - b;
    }
  }
  // z_q partial = +/- p2[R&15], sign from lane bits; fuse FC (scaled weights)
  f32x2 o2[4] = {{0.f,0.f},{0.f,0.f},{0.f,0.f},{0.f,0.f}};
  #pragma unroll
  for (int q = 0; q < NQ; ++q){
    constexpr int RALL[NQ] = {TAB.meas[0],TAB.meas[1],TAB.meas[2],TAB.meas[3],
                              TAB.meas[4],TAB.meas[5],TAB.meas[6],TAB.meas[7],
                              TAB.meas[8],TAB.meas[9]};
    int R = RALL[q];
    f32x2 tq = p2[R & 15];
    unsigned sg = (unsigned)(__popc((R >> 4) & lane) << 31);
    tq.x = __uint_as_float(__float_as_uint(tq.x) ^ sg);
    tq.y = __uint_as_float(__float_as_uint(tq.y) ^ sg);
    #pragma unroll
    for (int j = 0; j < 4; ++j) o2[j] = fma2(tq, bc(fcWs[j*NQ + q]), o2[j]);
  }
  // butterfly reduce (DPP for 1..8, one swizzle for 16, permlane for 32)
  #pragma unroll
  for (int j = 0; j < 4; ++j){
    o2[j].x += lxs<1>(o2[j].x);   o2[j].y += lxs<1>(o2[j].y);
    o2[j].x += lxs<2>(o2[j].x);   o2[j].y += lxs<2>(o2[j].y);
    o2[j].x += lxs<4>(o2[j].x);   o2[j].y += lxs<4>(o2[j].y);
    o2[j].x += lxs<8>(o2[j].x);   o2[j].y += lxs<8>(o2[j].y);
    o2[j].x += lxs<16>(o2[j].x);  o2[j].y += lxs<16>(o2[j].y);
    o2[j].x += lxs<32>(o2[j].x);  o2[j].y += lxs<32>(o2[j].y);
  }
  if (lane == 0){
    float4 a4 = make_float4(o2[0].x+fcB[0], o2[1].x+fcB[1], o2[2].x+fcB[2], o2[3].x+fcB[3]);
    float4 b4 = make_float4(o2[0].y+fcB[0], o2[1].y+fcB[1], o2[2].y+fcB[2], o2[3].y+fcB[3]);
    *reinterpret_cast<float4*>(&outB[(size_t)sA*4]) = a4;
    *reinterpret_cast<float4*>(&outB[(size_t)sB*4]) = b4;
  }
}

// ---- K3: deterministic BN stats (single block) ----
__global__ __launch_bounds__(1024) void k3_stats(const float* __restrict__ outB,
                                                 float* __restrict__ stats)
{
  int tid = threadIdx.x;
  float sum[4] = {0,0,0,0}, sq[4] = {0,0,0,0};
  for (int row = tid; row < B_SZ; row += 1024){
    float4 v = *reinterpret_cast<const float4*>(outB + (size_t)row*4);
    sum[0]+=v.x; sq[0]+=v.x*v.x;
    sum[1]+=v.y; sq[1]+=v.y*v.y;
    sum[2]+=v.z; sq[2]+=v.z*v.z;
    sum[3]+=v.w; sq[3]+=v.w*v.w;
  }
  #pragma unroll
  for (int k = 0; k < 4; ++k){
    #pragma unroll
    for (int st = 1; st < 64; st <<= 1){
      sum[k] += __shfl_xor(sum[k], st, 64);
      sq[k]  += __shfl_xor(sq[k],  st, 64);
    }
  }
  __shared__ float ls[16][8];
  int lane = tid & 63, w = tid >> 6;
  if (lane == 0){
    #pragma unroll
    for (int k = 0; k < 4; ++k){ ls[w][k] = sum[k]; ls[w][4+k] = sq[k]; }
  }
  __syncthreads();
  if (tid == 0){
    float fs[8];
    #pragma unroll
    for (int k = 0; k < 8; ++k){
      float a = 0.f;
      for (int w2 = 0; w2 < 16; ++w2) a += ls[w2][k];
      fs[k] = a;
    }
    #pragma unroll
    for (int k = 0; k < 4; ++k){
      float mean = fs[k] * (1.f/B_SZ);
      float var  = fs[4+k] * (1.f/B_SZ) - mean*mean;
      stats[k]   = mean;
      stats[4+k] = rsqrtf(var + 1e-5f);
    }
  }
}

// ---- K4: apply BN ----
__global__ __launch_bounds__(256) void k4_bn(const float* __restrict__ outB,
    const float* __restrict__ stats, const float* __restrict__ gamma,
    const float* __restrict__ beta, float* __restrict__ out)
{
  int idx = blockIdx.x * 256 + threadIdx.x;
  int c = idx & 3;
  float v = outB[idx];
  out[idx] = gamma[c] * (v - stats[c]) * stats[4+c] + beta[c];
}

extern "C" void kernel_launch(void* const* d_in, const int* in_sizes, int n_in,
                              void* d_out, int out_size, void* d_ws, size_t ws_size,
                              hipStream_t stream)
{
  const float* x     = (const float*)d_in[0];
  const float* encW  = (const float*)d_in[1];
  const float* encB  = (const float*)d_in[2];
  const float* wts   = (const float*)d_in[3];
  const float* fcW   = (const float*)d_in[4];
  const float* fcB   = (const float*)d_in[5];
  const float* gamma = (const float*)d_in[6];
  const float* beta  = (const float*)d_in[7];

  char* ws = (char*)d_ws;
  unsigned* gkey  = (unsigned*)ws;                      // 4 B
  float4*  U0     = (float4*)(ws + 256);                // 320 B
  float*   gcT    = (float*)(ws + 1024);                // 200 B
  float*   fcWs   = (float*)(ws + 2048);                // 160 B
  float4*  phase  = (float4*)(ws + 4096);               // 64 KB (c,c,s,s)
  float*   enc    = (float*)(ws + 4096 + 65536);
  float*   outB   = (float*)(ws + 4096 + 65536 + (size_t)B_SZ*NQ*4);
  float*   stats  = (float*)(ws + 4096 + 65536 + (size_t)B_SZ*NQ*4 + (size_t)B_SZ*4*4);

  hipLaunchKernelGGL(k_prep, dim3(16), dim3(256), 0, stream, wts, fcW, U0, gcT, phase, fcWs, gkey);
  hipLaunchKernelGGL(k1_encode, dim3(B_SZ/256), dim3(256), 0, stream,
                     x, encW, encB, enc, gkey);
  hipLaunchKernelGGL(k2_qsim, dim3(B_SZ/8), dim3(256), 0, stream,
                     enc, gkey, U0, gcT, phase, fcWs, fcB, outB);
  hipLaunchKernelGGL(k3_stats, dim3(1), dim3(1024), 0, stream, outB, stats);
  hipLaunchKernelGGL(k4_bn, dim3(B_SZ*4/256), dim3(256), 0, stream,
                     outB, stats, gamma, beta, (float*)d_out);
}

// Round 9
// 174.922 us; speedup vs baseline: 1.4356x; 1.1524x over previous
//
#include <hip/hip_runtime.h>
#include <math.h>

#define B_SZ 16384
#define NQ 10
#define DEPTH 6

typedef float f32x2 __attribute__((ext_vector_type(2)));

__device__ __forceinline__ f32x2 bc(float x){ return (f32x2){x, x}; }
__device__ __forceinline__ f32x2 fma2(f32x2 a, f32x2 b, f32x2 c){
  return __builtin_elementwise_fma(a, b, c);
}

// ---- constexpr GF(2) tracking of the CNOT ring (sequential, matches ref) ----
struct Tables {
  int m[DEPTH][NQ];   // phys xor-mask for gate on logical q at layer d
  int R[DEPTH][NQ];   // logical bit q of phys p = parity(R & p)
  int meas[NQ];       // final-basis rows for measurement
};
constexpr Tables make_tables(){
  Tables t{};
  int cols[NQ] = {}, rows[NQ] = {};
  for (int i = 0; i < NQ; ++i){ cols[i] = 1 << i; rows[i] = 1 << i; }
  for (int d = 0; d < DEPTH; ++d){
    for (int q = 0; q < NQ; ++q){ t.m[d][q] = cols[q]; t.R[d][q] = rows[q]; }
    for (int c = 0; c < NQ; ++c){          // ring: (0,1)..(8,9),(9,0)
      int tt = (c + 1) % NQ;
      cols[c]  ^= cols[tt];
      rows[tt] ^= rows[c];
    }
  }
  for (int q = 0; q < NQ; ++q) t.meas[q] = rows[q];
  return t;
}
constexpr Tables TAB = make_tables();

// ---- storage-basis change Phi ----
// storage bits: 0-3 = logical 0-3 (reg); 4-7 = logical 5-8 (cheap lane l0-l3);
// 8 = logical 9 (lane l4); 9 = parity of ALL logical bits (lane l5).
// Logical 4 is parity-encoded: n4 = popc(storage index) & 1.
// Gate mask (vector) transform: Phi(m)
constexpr int SM(int m){
  return (m & 0xF) | (((m >> 5) & 0xF) << 4) | (((m >> 9) & 1) << 8)
       | ((__builtin_popcount(m) & 1) << 9);
}
// Functional (row-vector) transform: f(n) = parity(F & n) == parity(FT(F) & s)
constexpr int FT(int F){
  int a4  = (F >> 4) & 1;
  int lo  = (F & 0xF)        ^ (a4 ? 0xF : 0);
  int mid = ((F >> 5) & 0xF) ^ (a4 ? 0xF : 0);
  int b8  = ((F >> 9) & 1) ^ a4;
  return lo | (mid << 4) | (b8 << 8) | (a4 << 9);
}

// ---- monotone float<->uint key for atomicMax over signed floats ----
__device__ __forceinline__ unsigned fkey(float x){
  unsigned b = __float_as_uint(x);
  return (b & 0x80000000u) ? ~b : (b | 0x80000000u);
}
__device__ __forceinline__ float funkey(unsigned k){
  unsigned b = (k & 0x80000000u) ? (k ^ 0x80000000u) : ~k;
  return __uint_as_float(b);
}

// ======== lane-xor machinery: DPP for masks 1..15, ds_bpermute otherwise ====
constexpr int quadctl(int m){ return (0^m) | ((1^m)<<2) | ((2^m)<<4) | ((3^m)<<6); }

template<int CTRL>
__device__ __forceinline__ float dppf(float x){
  return __uint_as_float((unsigned)__builtin_amdgcn_update_dpp(
      0, (int)__float_as_uint(x), CTRL, 0xF, 0xF, true));
}
template<int LM>   // 1..15 only (bits within a 16-lane row)
__device__ __forceinline__ float lxs(float x){
  if constexpr (LM == 0){
    return x;
  } else if constexpr (LM <= 3){
    return dppf<quadctl(LM)>(x);            // quad_perm xor 1..3
  } else if constexpr (LM == 7){
    return dppf<0x141>(x);                  // row_half_mirror: xor 7
  } else if constexpr (LM == 8){
    return dppf<0x128>(x);                  // row_ror:8 == xor 8
  } else if constexpr (LM == 15){
    return dppf<0x140>(x);                  // row_mirror: xor 15
  } else if constexpr ((LM & 12) == 4){
    return lxs<LM ^ 7>(dppf<0x141>(x));
  } else if constexpr ((LM & 12) == 8){
    return lxs<LM ^ 8>(dppf<0x128>(x));
  } else {
    return lxs<LM ^ 15>(dppf<0x140>(x));
  }
}
template<int LM>
__device__ __forceinline__ f32x2 lx2(f32x2 v){
  f32x2 r;
  r.x = lxs<LM>(v.x);
  r.y = lxs<LM>(v.y);
  return r;
}
// full 64-lane xor exchange via ds_bpermute (addr precomputed per gate)
__device__ __forceinline__ f32x2 lxd2(int adr, f32x2 v){
  f32x2 r;
  r.x = __uint_as_float((unsigned)__builtin_amdgcn_ds_bpermute(adr, (int)__float_as_uint(v.x)));
  r.y = __uint_as_float((unsigned)__builtin_amdgcn_ds_bpermute(adr, (int)__float_as_uint(v.y)));
  return r;
}

// ---- prep: U0, per-gate tangents, deferred-cos scaled FC weights, phases ----
__global__ __launch_bounds__(256) void k_prep(const float* __restrict__ wts,
    const float* __restrict__ fcW,
    float4* __restrict__ U0,     // 20: q*2+{0:(u00,u01),1:(u10,u11)}
    float* __restrict__ gcT,     // 50: (d-1)*10+q -> tan(ax)
    float4* __restrict__ phase,  // 4*1024: layers 1..4 diagonal (c,c,s,s)
    float* __restrict__ fcWs,    // 40: fcW * (prod cos)^2
    unsigned* __restrict__ gkey)
{
  int idx = blockIdx.x * 256 + threadIdx.x;
  if (idx < 4096){
    int layer = 1 + (idx >> 10);
    int p = idx & 1023;          // STORAGE index
    float phi = 0.f;
    for (int q = 0; q < NQ; ++q){
      float az = wts[(layer*NQ + q)*2 + 1] * 0.5f;
      int Fs = FT(TAB.R[layer][q]);
      phi += (__popc(Fs & p) & 1) ? az : -az;
    }
    float c = cosf(phi), s = sinf(phi);
    phase[idx] = make_float4(c, c, s, s);
  }
  if (blockIdx.x == 0){
    int t = threadIdx.x;
    if (t < NQ){
      float ax = wts[t*2+0]*0.5f, az = wts[t*2+1]*0.5f;
      float ca=cosf(ax), sa=sinf(ax), cz=cosf(az), sz=sinf(az);
      U0[t*2+0] = make_float4(ca*cz, -ca*sz, -sa*sz, -sa*cz); // u00r,u00i,u01r,u01i
      U0[t*2+1] = make_float4(sa*sz, -sa*cz,  ca*cz,  ca*sz); // u10r,u10i,u11r,u11i
    } else if (t >= 64 && t < 64 + 50){
      int g = t - 64;                     // (d-1)*10+q, d=1..5
      int d = 1 + g/10, q = g % 10;
      float ax = wts[(d*NQ+q)*2+0]*0.5f;
      gcT[g] = tanf(ax);
    } else if (t == 120){
      *gkey = 0u;
    } else if (t == 121){
      float pc = 1.f;
      for (int g = 0; g < 50; ++g){
        int d = 1 + g/10, q = g % 10;
        pc *= cosf(wts[(d*NQ+q)*2+0]*0.5f);
      }
      float s2 = pc * pc;
      for (int j = 0; j < 40; ++j) fcWs[j] = fcW[j] * s2;
    }
  }
}

// ---- K1: pool -> encode -> global max ----
__global__ __launch_bounds__(256) void k1_encode(const float* __restrict__ x,
    const float* __restrict__ encW, const float* __restrict__ encB,
    float* __restrict__ encOut, unsigned* __restrict__ gkey)
{
  int s = blockIdx.x * 256 + threadIdx.x;
  const float* xs = x + (size_t)s * 784;
  float pool[16];
  #pragma unroll
  for (int i = 0; i < 16; ++i) pool[i] = 0.f;
  #pragma unroll
  for (int row = 0; row < 24; ++row){
    int p = row / 6;
    #pragma unroll
    for (int c4 = 0; c4 < 6; ++c4){
      float4 v = *reinterpret_cast<const float4*>(xs + row * 28 + c4 * 4);
      int c0 = c4 * 4;
      pool[p*4 + (c0+0)/6] += v.x;
      pool[p*4 + (c0+1)/6] += v.y;
      pool[p*4 + (c0+2)/6] += v.z;
      pool[p*4 + (c0+3)/6] += v.w;
    }
  }
  #pragma unroll
  for (int i = 0; i < 16; ++i) pool[i] *= (1.f/36.f);

  float m = -INFINITY;
  #pragma unroll
  for (int i = 0; i < NQ; ++i){
    float e = encB[i];
    #pragma unroll
    for (int k = 0; k < 16; ++k) e = fmaf(pool[k], encW[i*16+k], e);
    encOut[(size_t)s*NQ + i] = e;
    m = fmaxf(m, e);
  }
  #pragma unroll
  for (int st = 1; st < 64; st <<= 1) m = fmaxf(m, __shfl_xor(m, st, 64));
  __shared__ float wm[4];
  int lane = threadIdx.x & 63, w = threadIdx.x >> 6;
  if (lane == 0) wm[w] = m;
  __syncthreads();
  if (threadIdx.x == 0){
    float mm = fmaxf(fmaxf(wm[0], wm[1]), fmaxf(wm[2], wm[3]));
    atomicMax(gkey, fkey(mm));
  }
}

// ---- Rx gate, tangent form, storage basis ----
template<int D, int Q>
__device__ __forceinline__ void rx_gate(f32x2 (&re)[16], f32x2 (&im)[16],
    const float* __restrict__ gcT, int lane)
{
  constexpr int ms = SM(TAB.m[D][Q]);
  constexpr int rm = ms & 15;
  constexpr int lm = (ms >> 4) & 63;
  float Tt = gcT[(D-1)*NQ + Q];     // wave-uniform
  f32x2 T = bc(Tt), nT = bc(-Tt);

  if constexpr (lm == 0){
    constexpr int lb = rm & (-rm);
    #pragma unroll
    for (int r = 0; r < 16; ++r) if (!(r & lb)){
      int r2 = r ^ rm;
      f32x2 ar = re[r],  ai = im[r];
      f32x2 br = re[r2], bi = im[r2];
      re[r]  = fma2(T,  bi, ar);
      im[r]  = fma2(nT, br, ai);
      re[r2] = fma2(T,  ai, br);
      im[r2] = fma2(nT, ar, bi);
    }
  } else if constexpr (lm < 16){
    if constexpr (rm == 0){
      #pragma unroll
      for (int r = 0; r < 16; ++r){
        f32x2 bi = lx2<lm>(im[r]);
        f32x2 br = lx2<lm>(re[r]);
        re[r] = fma2(T,  bi, re[r]);
        im[r] = fma2(nT, br, im[r]);
      }
    } else {
      constexpr int lb = rm & (-rm);
      #pragma unroll
      for (int r = 0; r < 16; ++r) if (!(r & lb)){
        int r2 = r ^ rm;
        f32x2 bi2 = lx2<lm>(im[r2]);
        f32x2 br2 = lx2<lm>(re[r2]);
        f32x2 bi1 = lx2<lm>(im[r]);
        f32x2 br1 = lx2<lm>(re[r]);
        re[r]  = fma2(T,  bi2, re[r]);
        im[r]  = fma2(nT, br2, im[r]);
        re[r2] = fma2(T,  bi1, re[r2]);
        im[r2] = fma2(nT, br1, im[r2]);
      }
    }
  } else {
    const int adr = (lane ^ lm) << 2;     // one ds_bpermute addr per gate
    if constexpr (rm == 0){
      #pragma unroll
      for (int r = 0; r < 16; ++r){
        f32x2 bi = lxd2(adr, im[r]);
        f32x2 br = lxd2(adr, re[r]);
        re[r] = fma2(T,  bi, re[r]);
        im[r] = fma2(nT, br, im[r]);
      }
    } else {
      constexpr int lb = rm & (-rm);
      #pragma unroll
      for (int r = 0; r < 16; ++r) if (!(r & lb)){
        int r2 = r ^ rm;
        f32x2 bi2 = lxd2(adr, im[r2]);
        f32x2 br2 = lxd2(adr, re[r2]);
        f32x2 bi1 = lxd2(adr, im[r]);
        f32x2 br1 = lxd2(adr, re[r]);
        re[r]  = fma2(T,  bi2, re[r]);
        im[r]  = fma2(nT, br2, im[r]);
        re[r2] = fma2(T,  bi1, re[r2]);
        im[r2] = fma2(nT, br1, im[r2]);
      }
    }
  }
}

template<int D>
__device__ __forceinline__ void run_layer(f32x2 (&re)[16], f32x2 (&im)[16],
    const float* __restrict__ gcT, const float4* __restrict__ phase4, int lane)
{
  rx_gate<D,0>(re, im, gcT, lane);
  rx_gate<D,1>(re, im, gcT, lane);
  rx_gate<D,2>(re, im, gcT, lane);
  rx_gate<D,3>(re, im, gcT, lane);
  rx_gate<D,4>(re, im, gcT, lane);
  rx_gate<D,5>(re, im, gcT, lane);
  rx_gate<D,6>(re, im, gcT, lane);
  rx_gate<D,7>(re, im, gcT, lane);
  rx_gate<D,8>(re, im, gcT, lane);
  rx_gate<D,9>(re, im, gcT, lane);
  if constexpr (D <= 4){
    const float4* __restrict__ pp = phase4 + (size_t)(D-1)*1024 + lane*16;
    #pragma unroll
    for (int r = 0; r < 16; ++r){
      float4 ph = pp[r];
      f32x2 cp = {ph.x, ph.y};
      f32x2 sp = {ph.z, ph.w};
      f32x2 ar = re[r], ai = im[r];
      re[r] = fma2(-sp, ai, cp*ar);
      im[r] = fma2( sp, ar, cp*ai);
    }
  }
  // D == 5: final diagonal dropped — phases don't affect |amp|^2
}

// ---- K2: one wave per TWO samples (packed in f32x2 components) ----
// storage amp index: bits[3:0] = register, bits[9:4] = lane (bit9 = parity bit)
__global__ __launch_bounds__(256) void k2_qsim(
    const float* __restrict__ enc, const unsigned* __restrict__ gkey,
    const float4* __restrict__ U0, const float* __restrict__ gcT,
    const float4* __restrict__ phase4,
    const float* __restrict__ fcWs, const float* __restrict__ fcB,
    float* __restrict__ outB)
{
  int tid  = threadIdx.x;
  int lane = tid & 63;
  int wid  = tid >> 6;
  int sA   = blockIdx.x * 8 + wid * 2;
  int sB   = sA + 1;

  float invr = 3.14159265358979f / (funkey(*gkey) + 1e-8f); // half-angle scale

  // spinor helper data loaded per qubit on the fly
  // lane bits 0..3 -> logical 5..8 ; lane bit 4 -> logical 9 ; bit 5 = parity bit
  f32x2 lr, li;
  {
    #pragma unroll
    for (int j = 0; j < 5; ++j){
      int q = (j < 4) ? (5 + j) : 9;
      float angA = enc[(size_t)sA*NQ + q] * invr;
      float angB = enc[(size_t)sB*NQ + q] * invr;
      f32x2 cv = {__cosf(angA), __cosf(angB)};
      f32x2 sv = {__sinf(angA), __sinf(angB)};
      float4 a = U0[q*2+0], b = U0[q*2+1];
      f32x2 pa_r = fma2(bc(a.z), sv, bc(a.x)*cv);
      f32x2 pa_i = fma2(bc(a.w), sv, bc(a.y)*cv);
      f32x2 pb_r = fma2(bc(b.z), sv, bc(b.x)*cv);
      f32x2 pb_i = fma2(bc(b.w), sv, bc(b.y)*cv);
      bool bit = (lane >> j) & 1;
      f32x2 fr = bit ? pb_r : pa_r;
      f32x2 fi = bit ? pb_i : pa_i;
      if (j == 0){ lr = fr; li = fi; }
      else {
        f32x2 t = lr*fr - li*fi;
        li = fma2(lr, fi, li*fr);
        lr = t;
      }
    }
  }

  // parity-encoded qubit 4: n4 = popc(storage idx)&1 = popc(lane)&1 ^ popc(r)&1
  f32x2 A0r, A0i, A1r, A1i;
  {
    float angA = enc[(size_t)sA*NQ + 4] * invr;
    float angB = enc[(size_t)sB*NQ + 4] * invr;
    f32x2 cv = {__cosf(angA), __cosf(angB)};
    f32x2 sv = {__sinf(angA), __sinf(angB)};
    float4 a = U0[8], b = U0[9];
    f32x2 pa_r = fma2(bc(a.z), sv, bc(a.x)*cv);
    f32x2 pa_i = fma2(bc(a.w), sv, bc(a.y)*cv);
    f32x2 pb_r = fma2(bc(b.z), sv, bc(b.x)*cv);
    f32x2 pb_i = fma2(bc(b.w), sv, bc(b.y)*cv);
    bool e = __popc(lane) & 1;         // lane parity (incl bits 4,5)
    A0r = e ? pb_r : pa_r;  A0i = e ? pb_i : pa_i;   // for even popc(r)
    A1r = e ? pa_r : pb_r;  A1i = e ? pa_i : pb_i;   // for odd popc(r)
  }

  // register-qubit product tree (logical 0..3 on reg bits 0..3)
  f32x2 re[16], im[16];
  re[0] = lr; im[0] = li;
  #pragma unroll
  for (int k = 0; k < 4; ++k){
    float angA = enc[(size_t)sA*NQ + k] * invr;
    float angB = enc[(size_t)sB*NQ + k] * invr;
    f32x2 cv = {__cosf(angA), __cosf(angB)};
    f32x2 sv = {__sinf(angA), __sinf(angB)};
    float4 a = U0[k*2+0], b = U0[k*2+1];
    f32x2 pa_r = fma2(bc(a.z), sv, bc(a.x)*cv);
    f32x2 pa_i = fma2(bc(a.w), sv, bc(a.y)*cv);
    f32x2 pb_r = fma2(bc(b.z), sv, bc(b.x)*cv);
    f32x2 pb_i = fma2(bc(b.w), sv, bc(b.y)*cv);
    int w = 1 << k;
    #pragma unroll
    for (int r = 0; r < 8; ++r) if (r < w){
      f32x2 xr = re[r], xi = im[r];
      re[r|w] = xr*pb_r - xi*pb_i;
      im[r|w] = fma2(xr, pb_i, xi*pb_r);
      re[r]   = xr*pa_r - xi*pa_i;
      im[r]   = fma2(xr, pa_i, xi*pa_r);
    }
  }
  // fold in the parity qubit factor (selection is compile-time per r)
  #pragma unroll
  for (int r = 0; r < 16; ++r){
    f32x2 sr = (__builtin_popcount(r) & 1) ? A1r : A0r;
    f32x2 si = (__builtin_popcount(r) & 1) ? A1i : A0i;
    f32x2 xr = re[r], xi = im[r];
    re[r] = xr*sr - xi*si;
    im[r] = fma2(xr, si, xi*sr);
  }

  run_layer<1>(re, im, gcT, phase4, lane);
  run_layer<2>(re, im, gcT, phase4, lane);
  run_layer<3>(re, im, gcT, phase4, lane);
  run_layer<4>(re, im, gcT, phase4, lane);
  run_layer<5>(re, im, gcT, phase4, lane);

  // probabilities -> 16-point WHT over register bits (packed)
  f32x2 p2[16];
  #pragma unroll
  for (int r = 0; r < 16; ++r) p2[r] = fma2(re[r], re[r], im[r]*im[r]);
  #pragma unroll
  for (int k = 0; k < 4; ++k){
    int w = 1 << k;
    #pragma unroll
    for (int r = 0; r < 16; ++r) if (!(r & w)){
      f32x2 a = p2[r], b = p2[r|w];
      p2[r] = a + b; p2[r|w] = a - b;
    }
  }
  // z_q partial = +/- p2[Rs&15], sign from storage lane bits; fuse FC
  f32x2 o2[4] = {{0.f,0.f},{0.f,0.f},{0.f,0.f},{0.f,0.f}};
  #pragma unroll
  for (int q = 0; q < NQ; ++q){
    constexpr int RALL[NQ] = {FT(TAB.meas[0]),FT(TAB.meas[1]),FT(TAB.meas[2]),
                              FT(TAB.meas[3]),FT(TAB.meas[4]),FT(TAB.meas[5]),
                              FT(TAB.meas[6]),FT(TAB.meas[7]),FT(TAB.meas[8]),
                              FT(TAB.meas[9])};
    int R = RALL[q];
    f32x2 tq = p2[R & 15];
    unsigned sg = (unsigned)(__popc((R >> 4) & lane) << 31);
    tq.x = __uint_as_float(__float_as_uint(tq.x) ^ sg);
    tq.y = __uint_as_float(__float_as_uint(tq.y) ^ sg);
    #pragma unroll
    for (int j = 0; j < 4; ++j) o2[j] = fma2(tq, bc(fcWs[j*NQ + q]), o2[j]);
  }
  #pragma unroll
  for (int j = 0; j < 4; ++j){
    #pragma unroll
    for (int st = 1; st < 64; st <<= 1){
      o2[j].x += __shfl_xor(o2[j].x, st, 64);
      o2[j].y += __shfl_xor(o2[j].y, st, 64);
    }
  }
  if (lane == 0){
    float4 a4 = make_float4(o2[0].x+fcB[0], o2[1].x+fcB[1], o2[2].x+fcB[2], o2[3].x+fcB[3]);
    float4 b4 = make_float4(o2[0].y+fcB[0], o2[1].y+fcB[1], o2[2].y+fcB[2], o2[3].y+fcB[3]);
    *reinterpret_cast<float4*>(&outB[(size_t)sA*4]) = a4;
    *reinterpret_cast<float4*>(&outB[(size_t)sB*4]) = b4;
  }
}

// ---- K3: deterministic BN stats (single block) ----
__global__ __launch_bounds__(1024) void k3_stats(const float* __restrict__ outB,
                                                 float* __restrict__ stats)
{
  int tid = threadIdx.x;
  float sum[4] = {0,0,0,0}, sq[4] = {0,0,0,0};
  for (int row = tid; row < B_SZ; row += 1024){
    float4 v = *reinterpret_cast<const float4*>(outB + (size_t)row*4);
    sum[0]+=v.x; sq[0]+=v.x*v.x;
    sum[1]+=v.y; sq[1]+=v.y*v.y;
    sum[2]+=v.z; sq[2]+=v.z*v.z;
    sum[3]+=v.w; sq[3]+=v.w*v.w;
  }
  #pragma unroll
  for (int k = 0; k < 4; ++k){
    #pragma unroll
    for (int st = 1; st < 64; st <<= 1){
      sum[k] += __shfl_xor(sum[k], st, 64);
      sq[k]  += __shfl_xor(sq[k],  st, 64);
    }
  }
  __shared__ float ls[16][8];
  int lane = tid & 63, w = tid >> 6;
  if (lane == 0){
    #pragma unroll
    for (int k = 0; k < 4; ++k){ ls[w][k] = sum[k]; ls[w][4+k] = sq[k]; }
  }
  __syncthreads();
  if (tid == 0){
    float fs[8];
    #pragma unroll
    for (int k = 0; k < 8; ++k){
      float a = 0.f;
      for (int w2 = 0; w2 < 16; ++w2) a += ls[w2][k];
      fs[k] = a;
    }
    #pragma unroll
    for (int k = 0; k < 4; ++k){
      float mean = fs[k] * (1.f/B_SZ);
      float var  = fs[4+k] * (1.f/B_SZ) - mean*mean;
      stats[k]   = mean;
      stats[4+k] = rsqrtf(var + 1e-5f);
    }
  }
}

// ---- K4: apply BN ----
__global__ __launch_bounds__(256) void k4_bn(const float* __restrict__ outB,
    const float* __restrict__ stats, const float* __restrict__ gamma,
    const float* __restrict__ beta, float* __restrict__ out)
{
  int idx = blockIdx.x * 256 + threadIdx.x;
  int c = idx & 3;
  float v = outB[idx];
  out[idx] = gamma[c] * (v - stats[c]) * stats[4+c] + beta[c];
}

extern "C" void kernel_launch(void* const* d_in, const int* in_sizes, int n_in,
                              void* d_out, int out_size, void* d_ws, size_t ws_size,
                              hipStream_t stream)
{
  const float* x     = (const float*)d_in[0];
  const float* encW  = (const float*)d_in[1];
  const float* encB  = (const float*)d_in[2];
  const float* wts   = (const float*)d_in[3];
  const float* fcW   = (const float*)d_in[4];
  const float* fcB   = (const float*)d_in[5];
  const float* gamma = (const float*)d_in[6];
  const float* beta  = (const float*)d_in[7];

  char* ws = (char*)d_ws;
  unsigned* gkey  = (unsigned*)ws;                      // 4 B
  float4*  U0     = (float4*)(ws + 256);                // 320 B
  float*   gcT    = (float*)(ws + 1024);                // 200 B
  float*   fcWs   = (float*)(ws + 2048);                // 160 B
  float4*  phase  = (float4*)(ws + 4096);               // 64 KB (c,c,s,s)
  float*   enc    = (float*)(ws + 4096 + 65536);
  float*   outB   = (float*)(ws + 4096 + 65536 + (size_t)B_SZ*NQ*4);
  float*   stats  = (float*)(ws + 4096 + 65536 + (size_t)B_SZ*NQ*4 + (size_t)B_SZ*4*4);

  hipLaunchKernelGGL(k_prep, dim3(16), dim3(256), 0, stream, wts, fcW, U0, gcT, phase, fcWs, gkey);
  hipLaunchKernelGGL(k1_encode, dim3(B_SZ/256), dim3(256), 0, stream,
                     x, encW, encB, enc, gkey);
  hipLaunchKernelGGL(k2_qsim, dim3(B_SZ/8), dim3(256), 0, stream,
                     enc, gkey, U0, gcT, phase, fcWs, fcB, outB);
  hipLaunchKernelGGL(k3_stats, dim3(1), dim3(1024), 0, stream, outB, stats);
  hipLaunchKernelGGL(k4_bn, dim3(B_SZ*4/256), dim3(256), 0, stream,
                     outB, stats, gamma, beta, (float*)d_out);
}

// Round 10
// 170.854 us; speedup vs baseline: 1.4698x; 1.0238x over previous
//
#include <hip/hip_runtime.h>
#include <math.h>

#define B_SZ 16384
#define NQ 10
#define DEPTH 6

typedef float f32x2 __attribute__((ext_vector_type(2)));

__device__ __forceinline__ f32x2 bc(float x){ return (f32x2){x, x}; }
__device__ __forceinline__ f32x2 fma2(f32x2 a, f32x2 b, f32x2 c){
  return __builtin_elementwise_fma(a, b, c);
}

// ---- constexpr GF(2) tracking of the CNOT ring (sequential, matches ref) ----
struct Tables {
  int m[DEPTH][NQ];   // phys xor-mask for gate on logical q at layer d
  int R[DEPTH][NQ];   // logical bit q of phys p = parity(R & p)
  int meas[NQ];       // final-basis rows for measurement
};
constexpr Tables make_tables(){
  Tables t{};
  int cols[NQ] = {}, rows[NQ] = {};
  for (int i = 0; i < NQ; ++i){ cols[i] = 1 << i; rows[i] = 1 << i; }
  for (int d = 0; d < DEPTH; ++d){
    for (int q = 0; q < NQ; ++q){ t.m[d][q] = cols[q]; t.R[d][q] = rows[q]; }
    for (int c = 0; c < NQ; ++c){          // ring: (0,1)..(8,9),(9,0)
      int tt = (c + 1) % NQ;
      cols[c]  ^= cols[tt];
      rows[tt] ^= rows[c];
    }
  }
  for (int q = 0; q < NQ; ++q) t.meas[q] = rows[q];
  return t;
}
constexpr Tables TAB = make_tables();

// ---- storage-basis change Phi (R9, proven) ----
// storage bits: 0-3 = logical 0-3 (reg); 4-7 = logical 5-8 (cheap lane l0-l3);
// 8 = logical 9 (lane l4); 9 = parity of ALL logical bits (lane l5).
constexpr int SM(int m){
  return (m & 0xF) | (((m >> 5) & 0xF) << 4) | (((m >> 9) & 1) << 8)
       | ((__builtin_popcount(m) & 1) << 9);
}
constexpr int FT(int F){
  int a4  = (F >> 4) & 1;
  int lo  = (F & 0xF)        ^ (a4 ? 0xF : 0);
  int mid = ((F >> 5) & 0xF) ^ (a4 ? 0xF : 0);
  int b8  = ((F >> 9) & 1) ^ a4;
  return lo | (mid << 4) | (b8 << 8) | (a4 << 9);
}

// ---- monotone float<->uint key for atomicMax over signed floats ----
__device__ __forceinline__ unsigned fkey(float x){
  unsigned b = __float_as_uint(x);
  return (b & 0x80000000u) ? ~b : (b | 0x80000000u);
}
__device__ __forceinline__ float funkey(unsigned k){
  unsigned b = (k & 0x80000000u) ? (k ^ 0x80000000u) : ~k;
  return __uint_as_float(b);
}

// ======== lane-xor machinery ========
// lm 1..15  : DPP (quad_perm / half_mirror / ror8 / mirror composites)
// lm 16..31 : permlane16_swap builtin (VALU) + DPP remainder; DS-swizzle fallback
// lm >= 32  : one ds_bpermute covering the whole mask
constexpr int quadctl(int m){ return (0^m) | ((1^m)<<2) | ((2^m)<<4) | ((3^m)<<6); }

template<int CTRL>
__device__ __forceinline__ float dppf(float x){
  return __uint_as_float((unsigned)__builtin_amdgcn_update_dpp(
      0, (int)__float_as_uint(x), CTRL, 0xF, 0xF, true));
}
template<int LM>     // 1..31: xor within 32-lane halves, single DS op
__device__ __forceinline__ float dsswz(float x){
  return __uint_as_float((unsigned)__builtin_amdgcn_ds_swizzle(
      (int)__float_as_uint(x), (LM << 10) | 0x1F));
}
template<int LM>   // 1..15
__device__ __forceinline__ float lxs(float x){
  if constexpr (LM == 0){
    return x;
  } else if constexpr (LM <= 3){
    return dppf<quadctl(LM)>(x);            // quad_perm xor 1..3
  } else if constexpr (LM == 7){
    return dppf<0x141>(x);                  // row_half_mirror: xor 7
  } else if constexpr (LM == 8){
    return dppf<0x128>(x);                  // row_ror:8 == xor 8
  } else if constexpr (LM == 15){
    return dppf<0x140>(x);                  // row_mirror: xor 15
  } else if constexpr ((LM & 12) == 4){
    return lxs<LM ^ 7>(dppf<0x141>(x));
  } else if constexpr ((LM & 12) == 8){
    return lxs<LM ^ 8>(dppf<0x128>(x));
  } else {
    return lxs<LM ^ 15>(dppf<0x140>(x));
  }
}
template<int LM>
__device__ __forceinline__ f32x2 lx2(f32x2 v){
  f32x2 r;
  r.x = lxs<LM>(v.x);
  r.y = lxs<LM>(v.y);
  return r;
}
#if __has_builtin(__builtin_amdgcn_permlane16_swap)
// xor-16 on VALU pipe: builtin returns both halves as SSA pair (no register
// aliasing possible); partner = r0^r1^x is swap-direction independent (R7 proof)
__device__ __forceinline__ float pl16(float x){
  unsigned u = __float_as_uint(x);
  auto r = __builtin_amdgcn_permlane16_swap(u, u, false, false);
  return __uint_as_float(r[0] ^ r[1] ^ u);
}
#endif
template<int LM>   // 16..31: bit4 + optional low bits
__device__ __forceinline__ f32x2 lxm(f32x2 v){
#if __has_builtin(__builtin_amdgcn_permlane16_swap)
  f32x2 t;
  t.x = pl16(v.x);
  t.y = pl16(v.y);
  return lx2<LM & 15>(t);
#else
  f32x2 r;                       // fallback: exact R9 behavior (one DS swizzle)
  r.x = dsswz<LM>(v.x);
  r.y = dsswz<LM>(v.y);
  return r;
#endif
}
template<int LM>   // generic VALU-tier exchange, LM < 32
__device__ __forceinline__ f32x2 lex(f32x2 v){
  if constexpr (LM < 16) return lx2<LM>(v);
  else                   return lxm<LM>(v);
}
// full 64-lane xor exchange via ds_bpermute (addr precomputed per gate)
__device__ __forceinline__ f32x2 lxd2(int adr, f32x2 v){
  f32x2 r;
  r.x = __uint_as_float((unsigned)__builtin_amdgcn_ds_bpermute(adr, (int)__float_as_uint(v.x)));
  r.y = __uint_as_float((unsigned)__builtin_amdgcn_ds_bpermute(adr, (int)__float_as_uint(v.y)));
  return r;
}

// ---- prep: U0, per-gate tangents, deferred-cos scaled FC weights, phases ----
__global__ __launch_bounds__(256) void k_prep(const float* __restrict__ wts,
    const float* __restrict__ fcW,
    float4* __restrict__ U0,     // 20: q*2+{0:(u00,u01),1:(u10,u11)}
    float* __restrict__ gcT,     // 50: (d-1)*10+q -> tan(ax)
    float4* __restrict__ phase,  // 4*1024: layers 1..4 diagonal (c,c,s,s)
    float* __restrict__ fcWs,    // 40: fcW * (prod cos)^2
    unsigned* __restrict__ gkey)
{
  int idx = blockIdx.x * 256 + threadIdx.x;
  if (idx < 4096){
    int layer = 1 + (idx >> 10);
    int p = idx & 1023;          // STORAGE index
    float phi = 0.f;
    for (int q = 0; q < NQ; ++q){
      float az = wts[(layer*NQ + q)*2 + 1] * 0.5f;
      int Fs = FT(TAB.R[layer][q]);
      phi += (__popc(Fs & p) & 1) ? az : -az;
    }
    float c = cosf(phi), s = sinf(phi);
    phase[idx] = make_float4(c, c, s, s);
  }
  if (blockIdx.x == 0){
    int t = threadIdx.x;
    if (t < NQ){
      float ax = wts[t*2+0]*0.5f, az = wts[t*2+1]*0.5f;
      float ca=cosf(ax), sa=sinf(ax), cz=cosf(az), sz=sinf(az);
      U0[t*2+0] = make_float4(ca*cz, -ca*sz, -sa*sz, -sa*cz); // u00r,u00i,u01r,u01i
      U0[t*2+1] = make_float4(sa*sz, -sa*cz,  ca*cz,  ca*sz); // u10r,u10i,u11r,u11i
    } else if (t >= 64 && t < 64 + 50){
      int g = t - 64;                     // (d-1)*10+q, d=1..5
      int d = 1 + g/10, q = g % 10;
      float ax = wts[(d*NQ+q)*2+0]*0.5f;
      gcT[g] = tanf(ax);
    } else if (t == 120){
      *gkey = 0u;
    } else if (t == 121){
      float pc = 1.f;
      for (int g = 0; g < 50; ++g){
        int d = 1 + g/10, q = g % 10;
        pc *= cosf(wts[(d*NQ+q)*2+0]*0.5f);
      }
      float s2 = pc * pc;
      for (int j = 0; j < 40; ++j) fcWs[j] = fcW[j] * s2;
    }
  }
}

// ---- K1: coalesced LDS-staged pool -> encode -> global max ----
// 1024 blocks x 256 thr; each wave stages ONE sample (wave-private LDS slice),
// 4 iterations -> 16 samples/block. All cross-lane traffic is within-wave.
__global__ __launch_bounds__(256) void k1_encode(const float* __restrict__ x,
    const float* __restrict__ encW, const float* __restrict__ encB,
    float* __restrict__ encOut, unsigned* __restrict__ gkey)
{
  __shared__ float lds[4][788];
  __shared__ float poolS[4][16];
  __shared__ float wmax[4];
  int tid = threadIdx.x, lane = tid & 63, wid = tid >> 6;
  float bm = -INFINITY;

  #pragma unroll 1
  for (int it = 0; it < 4; ++it){
    int s = blockIdx.x * 16 + it * 4 + wid;
    const float4* xs4 = reinterpret_cast<const float4*>(x + (size_t)s * 784);
    float4* l4 = reinterpret_cast<float4*>(lds[wid]);
    l4[lane]       = xs4[lane];          // 196 coalesced float4 per sample
    l4[lane + 64]  = xs4[lane + 64];
    l4[lane + 128] = xs4[lane + 128];
    if (lane < 4) l4[lane + 192] = xs4[lane + 192];
    __syncthreads();
    // pooling: bin b = lane&15, quarter sub = lane>>4 sums 9 of 36 elements
    int b = lane & 15, sub = lane >> 4;
    int r0 = (b >> 2) * 6, c0 = (b & 3) * 6;
    float acc = 0.f;
    #pragma unroll
    for (int k = 0; k < 9; ++k){
      int e = sub * 9 + k;
      acc += lds[wid][(r0 + e / 6) * 28 + c0 + e % 6];
    }
    acc += __shfl_xor(acc, 16, 64);
    acc += __shfl_xor(acc, 32, 64);
    if (lane < 16) poolS[wid][lane] = acc * (1.f/36.f);
    __syncthreads();
    // encode on lanes 0..9
    float ev = -INFINITY;
    if (lane < NQ){
      float e = encB[lane];
      #pragma unroll
      for (int k = 0; k < 16; ++k) e = fmaf(poolS[wid][k], encW[lane*16+k], e);
      encOut[(size_t)s*NQ + lane] = e;
      ev = e;
    }
    #pragma unroll
    for (int st = 1; st < 16; st <<= 1) ev = fmaxf(ev, __shfl_xor(ev, st, 64));
    bm = fmaxf(bm, ev);
  }
  if (lane == 0) wmax[wid] = bm;
  __syncthreads();
  if (tid == 0){
    float mm = fmaxf(fmaxf(wmax[0], wmax[1]), fmaxf(wmax[2], wmax[3]));
    atomicMax(gkey, fkey(mm));
  }
}

// ---- Rx gate, tangent form, storage basis, 3-tier exchanges ----
template<int D, int Q>
__device__ __forceinline__ void rx_gate(f32x2 (&re)[16], f32x2 (&im)[16],
    const float* __restrict__ gcT, int lane)
{
  constexpr int ms = SM(TAB.m[D][Q]);
  constexpr int rm = ms & 15;
  constexpr int lm = (ms >> 4) & 63;
  float Tt = gcT[(D-1)*NQ + Q];     // wave-uniform
  f32x2 T = bc(Tt), nT = bc(-Tt);

  if constexpr (lm == 0){
    constexpr int lb = rm & (-rm);
    #pragma unroll
    for (int r = 0; r < 16; ++r) if (!(r & lb)){
      int r2 = r ^ rm;
      f32x2 ar = re[r],  ai = im[r];
      f32x2 br = re[r2], bi = im[r2];
      re[r]  = fma2(T,  bi, ar);
      im[r]  = fma2(nT, br, ai);
      re[r2] = fma2(T,  ai, br);
      im[r2] = fma2(nT, ar, bi);
    }
  } else if constexpr (lm < 32){
    if constexpr (rm == 0){
      #pragma unroll
      for (int r = 0; r < 16; ++r){
        f32x2 bi = lex<lm>(im[r]);
        f32x2 br = lex<lm>(re[r]);
        re[r] = fma2(T,  bi, re[r]);
        im[r] = fma2(nT, br, im[r]);
      }
    } else {
      constexpr int lb = rm & (-rm);
      #pragma unroll
      for (int r = 0; r < 16; ++r) if (!(r & lb)){
        int r2 = r ^ rm;
        f32x2 bi2 = lex<lm>(im[r2]);
        f32x2 br2 = lex<lm>(re[r2]);
        f32x2 bi1 = lex<lm>(im[r]);
        f32x2 br1 = lex<lm>(re[r]);
        re[r]  = fma2(T,  bi2, re[r]);
        im[r]  = fma2(nT, br2, im[r]);
        re[r2] = fma2(T,  bi1, re[r2]);
        im[r2] = fma2(nT, br1, im[r2]);
      }
    }
  } else {
    const int adr = (lane ^ lm) << 2;     // one ds_bpermute addr per gate
    if constexpr (rm == 0){
      #pragma unroll
      for (int r = 0; r < 16; ++r){
        f32x2 bi = lxd2(adr, im[r]);
        f32x2 br = lxd2(adr, re[r]);
        re[r] = fma2(T,  bi, re[r]);
        im[r] = fma2(nT, br, im[r]);
      }
    } else {
      constexpr int lb = rm & (-rm);
      #pragma unroll
      for (int r = 0; r < 16; ++r) if (!(r & lb)){
        int r2 = r ^ rm;
        f32x2 bi2 = lxd2(adr, im[r2]);
        f32x2 br2 = lxd2(adr, re[r2]);
        f32x2 bi1 = lxd2(adr, im[r]);
        f32x2 br1 = lxd2(adr, re[r]);
        re[r]  = fma2(T,  bi2, re[r]);
        im[r]  = fma2(nT, br2, im[r]);
        re[r2] = fma2(T,  bi1, re[r2]);
        im[r2] = fma2(nT, br1, im[r2]);
      }
    }
  }
}

template<int D>
__device__ __forceinline__ void run_layer(f32x2 (&re)[16], f32x2 (&im)[16],
    const float* __restrict__ gcT, const float4* __restrict__ phase4, int lane)
{
  rx_gate<D,0>(re, im, gcT, lane);
  rx_gate<D,1>(re, im, gcT, lane);
  rx_gate<D,2>(re, im, gcT, lane);
  rx_gate<D,3>(re, im, gcT, lane);
  rx_gate<D,4>(re, im, gcT, lane);
  rx_gate<D,5>(re, im, gcT, lane);
  rx_gate<D,6>(re, im, gcT, lane);
  rx_gate<D,7>(re, im, gcT, lane);
  rx_gate<D,8>(re, im, gcT, lane);
  rx_gate<D,9>(re, im, gcT, lane);
  if constexpr (D <= 4){
    const float4* __restrict__ pp = phase4 + (size_t)(D-1)*1024 + lane*16;
    #pragma unroll
    for (int r = 0; r < 16; ++r){
      float4 ph = pp[r];
      f32x2 cp = {ph.x, ph.y};
      f32x2 sp = {ph.z, ph.w};
      f32x2 ar = re[r], ai = im[r];
      re[r] = fma2(-sp, ai, cp*ar);
      im[r] = fma2( sp, ar, cp*ai);
    }
  }
  // D == 5: final diagonal dropped — phases don't affect |amp|^2
}

// ---- K2: one wave per TWO samples (packed in f32x2 components) ----
// storage amp index: bits[3:0] = register, bits[9:4] = lane (bit9 = parity bit)
__global__ __launch_bounds__(256) void k2_qsim(
    const float* __restrict__ enc, const unsigned* __restrict__ gkey,
    const float4* __restrict__ U0, const float* __restrict__ gcT,
    const float4* __restrict__ phase4,
    const float* __restrict__ fcWs, const float* __restrict__ fcB,
    float* __restrict__ outB)
{
  int tid  = threadIdx.x;
  int lane = tid & 63;
  int wid  = tid >> 6;
  int sA   = blockIdx.x * 8 + wid * 2;
  int sB   = sA + 1;

  float invr = 3.14159265358979f / (funkey(*gkey) + 1e-8f); // half-angle scale

  // lane bits 0..3 -> logical 5..8 ; lane bit 4 -> logical 9 ; bit 5 = parity bit
  f32x2 lr, li;
  {
    #pragma unroll
    for (int j = 0; j < 5; ++j){
      int q = (j < 4) ? (5 + j) : 9;
      float angA = enc[(size_t)sA*NQ + q] * invr;
      float angB = enc[(size_t)sB*NQ + q] * invr;
      f32x2 cv = {__cosf(angA), __cosf(angB)};
      f32x2 sv = {__sinf(angA), __sinf(angB)};
      float4 a = U0[q*2+0], b = U0[q*2+1];
      f32x2 pa_r = fma2(bc(a.z), sv, bc(a.x)*cv);
      f32x2 pa_i = fma2(bc(a.w), sv, bc(a.y)*cv);
      f32x2 pb_r = fma2(bc(b.z), sv, bc(b.x)*cv);
      f32x2 pb_i = fma2(bc(b.w), sv, bc(b.y)*cv);
      bool bit = (lane >> j) & 1;
      f32x2 fr = bit ? pb_r : pa_r;
      f32x2 fi = bit ? pb_i : pa_i;
      if (j == 0){ lr = fr; li = fi; }
      else {
        f32x2 t = lr*fr - li*fi;
        li = fma2(lr, fi, li*fr);
        lr = t;
      }
    }
  }

  // parity-encoded qubit 4: n4 = popc(storage idx)&1 = popc(lane)&1 ^ popc(r)&1
  f32x2 A0r, A0i, A1r, A1i;
  {
    float angA = enc[(size_t)sA*NQ + 4] * invr;
    float angB = enc[(size_t)sB*NQ + 4] * invr;
    f32x2 cv = {__cosf(angA), __cosf(angB)};
    f32x2 sv = {__sinf(angA), __sinf(angB)};
    float4 a = U0[8], b = U0[9];
    f32x2 pa_r = fma2(bc(a.z), sv, bc(a.x)*cv);
    f32x2 pa_i = fma2(bc(a.w), sv, bc(a.y)*cv);
    f32x2 pb_r = fma2(bc(b.z), sv, bc(b.x)*cv);
    f32x2 pb_i = fma2(bc(b.w), sv, bc(b.y)*cv);
    bool e = __popc(lane) & 1;
    A0r = e ? pb_r : pa_r;  A0i = e ? pb_i : pa_i;
    A1r = e ? pa_r : pb_r;  A1i = e ? pa_i : pb_i;
  }

  // register-qubit product tree (logical 0..3 on reg bits 0..3)
  f32x2 re[16], im[16];
  re[0] = lr; im[0] = li;
  #pragma unroll
  for (int k = 0; k < 4; ++k){
    float angA = enc[(size_t)sA*NQ + k] * invr;
    float angB = enc[(size_t)sB*NQ + k] * invr;
    f32x2 cv = {__cosf(angA), __cosf(angB)};
    f32x2 sv = {__sinf(angA), __sinf(angB)};
    float4 a = U0[k*2+0], b = U0[k*2+1];
    f32x2 pa_r = fma2(bc(a.z), sv, bc(a.x)*cv);
    f32x2 pa_i = fma2(bc(a.w), sv, bc(a.y)*cv);
    f32x2 pb_r = fma2(bc(b.z), sv, bc(b.x)*cv);
    f32x2 pb_i = fma2(bc(b.w), sv, bc(b.y)*cv);
    int w = 1 << k;
    #pragma unroll
    for (int r = 0; r < 8; ++r) if (r < w){
      f32x2 xr = re[r], xi = im[r];
      re[r|w] = xr*pb_r - xi*pb_i;
      im[r|w] = fma2(xr, pb_i, xi*pb_r);
      re[r]   = xr*pa_r - xi*pa_i;
      im[r]   = fma2(xr, pa_i, xi*pa_r);
    }
  }
  // fold in the parity qubit factor (selection is compile-time per r)
  #pragma unroll
  for (int r = 0; r < 16; ++r){
    f32x2 sr = (__builtin_popcount(r) & 1) ? A1r : A0r;
    f32x2 si = (__builtin_popcount(r) & 1) ? A1i : A0i;
    f32x2 xr = re[r], xi = im[r];
    re[r] = xr*sr - xi*si;
    im[r] = fma2(xr, si, xi*sr);
  }

  run_layer<1>(re, im, gcT, phase4, lane);
  run_layer<2>(re, im, gcT, phase4, lane);
  run_layer<3>(re, im, gcT, phase4, lane);
  run_layer<4>(re, im, gcT, phase4, lane);
  run_layer<5>(re, im, gcT, phase4, lane);

  // probabilities -> 16-point WHT over register bits (packed)
  f32x2 p2[16];
  #pragma unroll
  for (int r = 0; r < 16; ++r) p2[r] = fma2(re[r], re[r], im[r]*im[r]);
  #pragma unroll
  for (int k = 0; k < 4; ++k){
    int w = 1 << k;
    #pragma unroll
    for (int r = 0; r < 16; ++r) if (!(r & w)){
      f32x2 a = p2[r], b = p2[r|w];
      p2[r] = a + b; p2[r|w] = a - b;
    }
  }
  // z_q partial = +/- p2[Rs&15], sign from storage lane bits; fuse FC
  f32x2 o2[4] = {{0.f,0.f},{0.f,0.f},{0.f,0.f},{0.f,0.f}};
  #pragma unroll
  for (int q = 0; q < NQ; ++q){
    constexpr int RALL[NQ] = {FT(TAB.meas[0]),FT(TAB.meas[1]),FT(TAB.meas[2]),
                              FT(TAB.meas[3]),FT(TAB.meas[4]),FT(TAB.meas[5]),
                              FT(TAB.meas[6]),FT(TAB.meas[7]),FT(TAB.meas[8]),
                              FT(TAB.meas[9])};
    int R = RALL[q];
    f32x2 tq = p2[R & 15];
    unsigned sg = (unsigned)(__popc((R >> 4) & lane) << 31);
    tq.x = __uint_as_float(__float_as_uint(tq.x) ^ sg);
    tq.y = __uint_as_float(__float_as_uint(tq.y) ^ sg);
    #pragma unroll
    for (int j = 0; j < 4; ++j) o2[j] = fma2(tq, bc(fcWs[j*NQ + q]), o2[j]);
  }
  #pragma unroll
  for (int j = 0; j < 4; ++j){
    #pragma unroll
    for (int st = 1; st < 64; st <<= 1){
      o2[j].x += __shfl_xor(o2[j].x, st, 64);
      o2[j].y += __shfl_xor(o2[j].y, st, 64);
    }
  }
  if (lane == 0){
    float4 a4 = make_float4(o2[0].x+fcB[0], o2[1].x+fcB[1], o2[2].x+fcB[2], o2[3].x+fcB[3]);
    float4 b4 = make_float4(o2[0].y+fcB[0], o2[1].y+fcB[1], o2[2].y+fcB[2], o2[3].y+fcB[3]);
    *reinterpret_cast<float4*>(&outB[(size_t)sA*4]) = a4;
    *reinterpret_cast<float4*>(&outB[(size_t)sB*4]) = b4;
  }
}

// ---- K3: deterministic BN stats (single block) ----
__global__ __launch_bounds__(1024) void k3_stats(const float* __restrict__ outB,
                                                 float* __restrict__ stats)
{
  int tid = threadIdx.x;
  float sum[4] = {0,0,0,0}, sq[4] = {0,0,0,0};
  for (int row = tid; row < B_SZ; row += 1024){
    float4 v = *reinterpret_cast<const float4*>(outB + (size_t)row*4);
    sum[0]+=v.x; sq[0]+=v.x*v.x;
    sum[1]+=v.y; sq[1]+=v.y*v.y;
    sum[2]+=v.z; sq[2]+=v.z*v.z;
    sum[3]+=v.w; sq[3]+=v.w*v.w;
  }
  #pragma unroll
  for (int k = 0; k < 4; ++k){
    #pragma unroll
    for (int st = 1; st < 64; st <<= 1){
      sum[k] += __shfl_xor(sum[k], st, 64);
      sq[k]  += __shfl_xor(sq[k],  st, 64);
    }
  }
  __shared__ float ls[16][8];
  int lane = tid & 63, w = tid >> 6;
  if (lane == 0){
    #pragma unroll
    for (int k = 0; k < 4; ++k){ ls[w][k] = sum[k]; ls[w][4+k] = sq[k]; }
  }
  __syncthreads();
  if (tid == 0){
    float fs[8];
    #pragma unroll
    for (int k = 0; k < 8; ++k){
      float a = 0.f;
      for (int w2 = 0; w2 < 16; ++w2) a += ls[w2][k];
      fs[k] = a;
    }
    #pragma unroll
    for (int k = 0; k < 4; ++k){
      float mean = fs[k] * (1.f/B_SZ);
      float var  = fs[4+k] * (1.f/B_SZ) - mean*mean;
      stats[k]   = mean;
      stats[4+k] = rsqrtf(var + 1e-5f);
    }
  }
}

// ---- K4: apply BN ----
__global__ __launch_bounds__(256) void k4_bn(const float* __restrict__ outB,
    const float* __restrict__ stats, const float* __restrict__ gamma,
    const float* __restrict__ beta, float* __restrict__ out)
{
  int idx = blockIdx.x * 256 + threadIdx.x;
  int c = idx & 3;
  float v = outB[idx];
  out[idx] = gamma[c] * (v - stats[c]) * stats[4+c] + beta[c];
}

extern "C" void kernel_launch(void* const* d_in, const int* in_sizes, int n_in,
                              void* d_out, int out_size, void* d_ws, size_t ws_size,
                              hipStream_t stream)
{
  const float* x     = (const float*)d_in[0];
  const float* encW  = (const float*)d_in[1];
  const float* encB  = (const float*)d_in[2];
  const float* wts   = (const float*)d_in[3];
  const float* fcW   = (const float*)d_in[4];
  const float* fcB   = (const float*)d_in[5];
  const float* gamma = (const float*)d_in[6];
  const float* beta  = (const float*)d_in[7];

  char* ws = (char*)d_ws;
  unsigned* gkey  = (unsigned*)ws;                      // 4 B
  float4*  U0     = (float4*)(ws + 256);                // 320 B
  float*   gcT    = (float*)(ws + 1024);                // 200 B
  float*   fcWs   = (float*)(ws + 2048);                // 160 B
  float4*  phase  = (float4*)(ws + 4096);               // 64 KB (c,c,s,s)
  float*   enc    = (float*)(ws + 4096 + 65536);
  float*   outB   = (float*)(ws + 4096 + 65536 + (size_t)B_SZ*NQ*4);
  float*   stats  = (float*)(ws + 4096 + 65536 + (size_t)B_SZ*NQ*4 + (size_t)B_SZ*4*4);

  hipLaunchKernelGGL(k_prep, dim3(16), dim3(256), 0, stream, wts, fcW, U0, gcT, phase, fcWs, gkey);
  hipLaunchKernelGGL(k1_encode, dim3(B_SZ/16), dim3(256), 0, stream,
                     x, encW, encB, enc, gkey);
  hipLaunchKernelGGL(k2_qsim, dim3(B_SZ/8), dim3(256), 0, stream,
                     enc, gkey, U0, gcT, phase, fcWs, fcB, outB);
  hipLaunchKernelGGL(k3_stats, dim3(1), dim3(1024), 0, stream, outB, stats);
  hipLaunchKernelGGL(k4_bn, dim3(B_SZ*4/256), dim3(256), 0, stream,
                     outB, stats, gamma, beta, (float*)d_out);
}

// Round 11
// 161.042 us; speedup vs baseline: 1.5593x; 1.0609x over previous
//
#include <hip/hip_runtime.h>
#include <math.h>

#define B_SZ 16384
#define NQ 10
#define DEPTH 6

typedef float f32x2 __attribute__((ext_vector_type(2)));

__device__ __forceinline__ f32x2 bc(float x){ return (f32x2){x, x}; }
__device__ __forceinline__ f32x2 fma2(f32x2 a, f32x2 b, f32x2 c){
  return __builtin_elementwise_fma(a, b, c);
}

// ---- constexpr GF(2) tracking of the CNOT ring (sequential, matches ref) ----
struct Tables {
  int m[DEPTH][NQ];   // phys xor-mask for gate on logical q at layer d
  int R[DEPTH][NQ];   // logical bit q of phys p = parity(R & p)
  int meas[NQ];       // final-basis rows for measurement
};
constexpr Tables make_tables(){
  Tables t{};
  int cols[NQ] = {}, rows[NQ] = {};
  for (int i = 0; i < NQ; ++i){ cols[i] = 1 << i; rows[i] = 1 << i; }
  for (int d = 0; d < DEPTH; ++d){
    for (int q = 0; q < NQ; ++q){ t.m[d][q] = cols[q]; t.R[d][q] = rows[q]; }
    for (int c = 0; c < NQ; ++c){          // ring: (0,1)..(8,9),(9,0)
      int tt = (c + 1) % NQ;
      cols[c]  ^= cols[tt];
      rows[tt] ^= rows[c];
    }
  }
  for (int q = 0; q < NQ; ++q) t.meas[q] = rows[q];
  return t;
}
constexpr Tables TAB = make_tables();

// ---- storage-basis change Phi (R9, proven) ----
// storage bits: 0-3 = logical 0-3 (reg); 4-7 = logical 5-8 (cheap lane l0-l3);
// 8 = logical 9 (lane l4); 9 = parity of ALL logical bits (lane l5).
constexpr int SM(int m){
  return (m & 0xF) | (((m >> 5) & 0xF) << 4) | (((m >> 9) & 1) << 8)
       | ((__builtin_popcount(m) & 1) << 9);
}
constexpr int FT(int F){
  int a4  = (F >> 4) & 1;
  int lo  = (F & 0xF)        ^ (a4 ? 0xF : 0);
  int mid = ((F >> 5) & 0xF) ^ (a4 ? 0xF : 0);
  int b8  = ((F >> 9) & 1) ^ a4;
  return lo | (mid << 4) | (b8 << 8) | (a4 << 9);
}

// ---- monotone float<->uint key for atomicMax over signed floats ----
__device__ __forceinline__ unsigned fkey(float x){
  unsigned b = __float_as_uint(x);
  return (b & 0x80000000u) ? ~b : (b | 0x80000000u);
}
__device__ __forceinline__ float funkey(unsigned k){
  unsigned b = (k & 0x80000000u) ? (k ^ 0x80000000u) : ~k;
  return __uint_as_float(b);
}

// ======== lane-xor machinery: DPP for masks 1..15, ds_bpermute otherwise ====
// (exact R9 tier assignment — R10's permlane16 tier regressed, reverted)
constexpr int quadctl(int m){ return (0^m) | ((1^m)<<2) | ((2^m)<<4) | ((3^m)<<6); }

template<int CTRL>
__device__ __forceinline__ float dppf(float x){
  return __uint_as_float((unsigned)__builtin_amdgcn_update_dpp(
      0, (int)__float_as_uint(x), CTRL, 0xF, 0xF, true));
}
template<int LM>   // 1..15 only (bits within a 16-lane row)
__device__ __forceinline__ float lxs(float x){
  if constexpr (LM == 0){
    return x;
  } else if constexpr (LM <= 3){
    return dppf<quadctl(LM)>(x);            // quad_perm xor 1..3
  } else if constexpr (LM == 7){
    return dppf<0x141>(x);                  // row_half_mirror: xor 7
  } else if constexpr (LM == 8){
    return dppf<0x128>(x);                  // row_ror:8 == xor 8
  } else if constexpr (LM == 15){
    return dppf<0x140>(x);                  // row_mirror: xor 15
  } else if constexpr ((LM & 12) == 4){
    return lxs<LM ^ 7>(dppf<0x141>(x));
  } else if constexpr ((LM & 12) == 8){
    return lxs<LM ^ 8>(dppf<0x128>(x));
  } else {
    return lxs<LM ^ 15>(dppf<0x140>(x));
  }
}
template<int LM>
__device__ __forceinline__ f32x2 lx2(f32x2 v){
  f32x2 r;
  r.x = lxs<LM>(v.x);
  r.y = lxs<LM>(v.y);
  return r;
}
// full 64-lane xor exchange via ds_bpermute (addr precomputed per gate)
__device__ __forceinline__ f32x2 lxd2(int adr, f32x2 v){
  f32x2 r;
  r.x = __uint_as_float((unsigned)__builtin_amdgcn_ds_bpermute(adr, (int)__float_as_uint(v.x)));
  r.y = __uint_as_float((unsigned)__builtin_amdgcn_ds_bpermute(adr, (int)__float_as_uint(v.y)));
  return r;
}

// ---- prep: U0, per-gate tangents, deferred-cos scaled FC weights, phases ----
__global__ __launch_bounds__(256) void k_prep(const float* __restrict__ wts,
    const float* __restrict__ fcW,
    float4* __restrict__ U0,     // 20: q*2+{0:(u00,u01),1:(u10,u11)}
    float* __restrict__ gcT,     // 50: (d-1)*10+q -> tan(ax)
    float4* __restrict__ phase,  // 4*1024: layers 1..4 diagonal (c,c,s,s)
    float* __restrict__ fcWs,    // 40: fcW * (prod cos)^2
    unsigned* __restrict__ gkey)
{
  int idx = blockIdx.x * 256 + threadIdx.x;
  if (idx < 4096){
    int layer = 1 + (idx >> 10);
    int p = idx & 1023;          // STORAGE index
    float phi = 0.f;
    for (int q = 0; q < NQ; ++q){
      float az = wts[(layer*NQ + q)*2 + 1] * 0.5f;
      int Fs = FT(TAB.R[layer][q]);
      phi += (__popc(Fs & p) & 1) ? az : -az;
    }
    float c = cosf(phi), s = sinf(phi);
    phase[idx] = make_float4(c, c, s, s);
  }
  if (blockIdx.x == 0){
    int t = threadIdx.x;
    if (t < NQ){
      float ax = wts[t*2+0]*0.5f, az = wts[t*2+1]*0.5f;
      float ca=cosf(ax), sa=sinf(ax), cz=cosf(az), sz=sinf(az);
      U0[t*2+0] = make_float4(ca*cz, -ca*sz, -sa*sz, -sa*cz); // u00r,u00i,u01r,u01i
      U0[t*2+1] = make_float4(sa*sz, -sa*cz,  ca*cz,  ca*sz); // u10r,u10i,u11r,u11i
    } else if (t >= 64 && t < 64 + 50){
      int g = t - 64;                     // (d-1)*10+q, d=1..5
      int d = 1 + g/10, q = g % 10;
      float ax = wts[(d*NQ+q)*2+0]*0.5f;
      gcT[g] = tanf(ax);
    } else if (t == 120){
      *gkey = 0u;
    } else if (t == 121){
      float pc = 1.f;
      for (int g = 0; g < 50; ++g){
        int d = 1 + g/10, q = g % 10;
        pc *= cosf(wts[(d*NQ+q)*2+0]*0.5f);
      }
      float s2 = pc * pc;
      for (int j = 0; j < 40; ++j) fcWs[j] = fcW[j] * s2;
    }
  }
}

// ---- K1: coalesced LDS-staged pool -> encode -> global max (R10, proven) ----
__global__ __launch_bounds__(256) void k1_encode(const float* __restrict__ x,
    const float* __restrict__ encW, const float* __restrict__ encB,
    float* __restrict__ encOut, unsigned* __restrict__ gkey)
{
  __shared__ float lds[4][788];
  __shared__ float poolS[4][16];
  __shared__ float wmax[4];
  int tid = threadIdx.x, lane = tid & 63, wid = tid >> 6;
  float bm = -INFINITY;

  #pragma unroll 1
  for (int it = 0; it < 4; ++it){
    int s = blockIdx.x * 16 + it * 4 + wid;
    const float4* xs4 = reinterpret_cast<const float4*>(x + (size_t)s * 784);
    float4* l4 = reinterpret_cast<float4*>(lds[wid]);
    l4[lane]       = xs4[lane];          // 196 coalesced float4 per sample
    l4[lane + 64]  = xs4[lane + 64];
    l4[lane + 128] = xs4[lane + 128];
    if (lane < 4) l4[lane + 192] = xs4[lane + 192];
    __syncthreads();
    int b = lane & 15, sub = lane >> 4;
    int r0 = (b >> 2) * 6, c0 = (b & 3) * 6;
    float acc = 0.f;
    #pragma unroll
    for (int k = 0; k < 9; ++k){
      int e = sub * 9 + k;
      acc += lds[wid][(r0 + e / 6) * 28 + c0 + e % 6];
    }
    acc += __shfl_xor(acc, 16, 64);
    acc += __shfl_xor(acc, 32, 64);
    if (lane < 16) poolS[wid][lane] = acc * (1.f/36.f);
    __syncthreads();
    float ev = -INFINITY;
    if (lane < NQ){
      float e = encB[lane];
      #pragma unroll
      for (int k = 0; k < 16; ++k) e = fmaf(poolS[wid][k], encW[lane*16+k], e);
      encOut[(size_t)s*NQ + lane] = e;
      ev = e;
    }
    #pragma unroll
    for (int st = 1; st < 16; st <<= 1) ev = fmaxf(ev, __shfl_xor(ev, st, 64));
    bm = fmaxf(bm, ev);
  }
  if (lane == 0) wmax[wid] = bm;
  __syncthreads();
  if (tid == 0){
    float mm = fmaxf(fmaxf(wmax[0], wmax[1]), fmaxf(wmax[2], wmax[3]));
    atomicMax(gkey, fkey(mm));
  }
}

// ---- Rx gate, tangent form, storage basis (R9 tiers) ----
template<int D, int Q>
__device__ __forceinline__ void rx_gate(f32x2 (&re)[16], f32x2 (&im)[16],
    const float* __restrict__ gcT, int lane)
{
  constexpr int ms = SM(TAB.m[D][Q]);
  constexpr int rm = ms & 15;
  constexpr int lm = (ms >> 4) & 63;
  float Tt = gcT[(D-1)*NQ + Q];     // wave-uniform
  f32x2 T = bc(Tt), nT = bc(-Tt);

  if constexpr (lm == 0){
    constexpr int lb = rm & (-rm);
    #pragma unroll
    for (int r = 0; r < 16; ++r) if (!(r & lb)){
      int r2 = r ^ rm;
      f32x2 ar = re[r],  ai = im[r];
      f32x2 br = re[r2], bi = im[r2];
      re[r]  = fma2(T,  bi, ar);
      im[r]  = fma2(nT, br, ai);
      re[r2] = fma2(T,  ai, br);
      im[r2] = fma2(nT, ar, bi);
    }
  } else if constexpr (lm < 16){
    if constexpr (rm == 0){
      #pragma unroll
      for (int r = 0; r < 16; ++r){
        f32x2 bi = lx2<lm>(im[r]);
        f32x2 br = lx2<lm>(re[r]);
        re[r] = fma2(T,  bi, re[r]);
        im[r] = fma2(nT, br, im[r]);
      }
    } else {
      constexpr int lb = rm & (-rm);
      #pragma unroll
      for (int r = 0; r < 16; ++r) if (!(r & lb)){
        int r2 = r ^ rm;
        f32x2 bi2 = lx2<lm>(im[r2]);
        f32x2 br2 = lx2<lm>(re[r2]);
        f32x2 bi1 = lx2<lm>(im[r]);
        f32x2 br1 = lx2<lm>(re[r]);
        re[r]  = fma2(T,  bi2, re[r]);
        im[r]  = fma2(nT, br2, im[r]);
        re[r2] = fma2(T,  bi1, re[r2]);
        im[r2] = fma2(nT, br1, im[r2]);
      }
    }
  } else {
    const int adr = (lane ^ lm) << 2;     // one ds_bpermute addr per gate
    if constexpr (rm == 0){
      #pragma unroll
      for (int r = 0; r < 16; ++r){
        f32x2 bi = lxd2(adr, im[r]);
        f32x2 br = lxd2(adr, re[r]);
        re[r] = fma2(T,  bi, re[r]);
        im[r] = fma2(nT, br, im[r]);
      }
    } else {
      constexpr int lb = rm & (-rm);
      #pragma unroll
      for (int r = 0; r < 16; ++r) if (!(r & lb)){
        int r2 = r ^ rm;
        f32x2 bi2 = lxd2(adr, im[r2]);
        f32x2 br2 = lxd2(adr, re[r2]);
        f32x2 bi1 = lxd2(adr, im[r]);
        f32x2 br1 = lxd2(adr, re[r]);
        re[r]  = fma2(T,  bi2, re[r]);
        im[r]  = fma2(nT, br2, im[r]);
        re[r2] = fma2(T,  bi1, re[r2]);
        im[r2] = fma2(nT, br1, im[r2]);
      }
    }
  }
}

template<int D>
__device__ __forceinline__ void run_layer(f32x2 (&re)[16], f32x2 (&im)[16],
    const float* __restrict__ gcT, const float4* __restrict__ phase4, int lane)
{
  // issue the layer-diagonal loads BEFORE the gate chain so L2 latency hides
  float4 phv[16];
  if constexpr (D <= 4){
    const float4* __restrict__ pp = phase4 + (size_t)(D-1)*1024 + lane*16;
    #pragma unroll
    for (int r = 0; r < 16; ++r) phv[r] = pp[r];
  }
  rx_gate<D,0>(re, im, gcT, lane);
  rx_gate<D,1>(re, im, gcT, lane);
  rx_gate<D,2>(re, im, gcT, lane);
  rx_gate<D,3>(re, im, gcT, lane);
  rx_gate<D,4>(re, im, gcT, lane);
  rx_gate<D,5>(re, im, gcT, lane);
  rx_gate<D,6>(re, im, gcT, lane);
  rx_gate<D,7>(re, im, gcT, lane);
  rx_gate<D,8>(re, im, gcT, lane);
  rx_gate<D,9>(re, im, gcT, lane);
  if constexpr (D <= 4){
    #pragma unroll
    for (int r = 0; r < 16; ++r){
      float4 ph = phv[r];
      f32x2 cp = {ph.x, ph.y};
      f32x2 sp = {ph.z, ph.w};
      f32x2 ar = re[r], ai = im[r];
      re[r] = fma2(-sp, ai, cp*ar);
      im[r] = fma2( sp, ar, cp*ai);
    }
  }
  // D == 5: final diagonal dropped — phases don't affect |amp|^2
}

// ---- K2: one wave per TWO samples (packed in f32x2 components) ----
// storage amp index: bits[3:0] = register, bits[9:4] = lane (bit9 = parity bit)
__global__ __launch_bounds__(256) void k2_qsim(
    const float* __restrict__ enc, const unsigned* __restrict__ gkey,
    const float4* __restrict__ U0, const float* __restrict__ gcT,
    const float4* __restrict__ phase4,
    const float* __restrict__ fcWs, const float* __restrict__ fcB,
    float* __restrict__ outB)
{
  int tid  = threadIdx.x;
  int lane = tid & 63;
  int wid  = tid >> 6;
  int sA   = blockIdx.x * 8 + wid * 2;
  int sB   = sA + 1;

  float invr = 3.14159265358979f / (funkey(*gkey) + 1e-8f); // half-angle scale

  // lane bits 0..3 -> logical 5..8 ; lane bit 4 -> logical 9 ; bit 5 = parity bit
  f32x2 lr, li;
  {
    #pragma unroll
    for (int j = 0; j < 5; ++j){
      int q = (j < 4) ? (5 + j) : 9;
      float angA = enc[(size_t)sA*NQ + q] * invr;
      float angB = enc[(size_t)sB*NQ + q] * invr;
      f32x2 cv = {__cosf(angA), __cosf(angB)};
      f32x2 sv = {__sinf(angA), __sinf(angB)};
      float4 a = U0[q*2+0], b = U0[q*2+1];
      f32x2 pa_r = fma2(bc(a.z), sv, bc(a.x)*cv);
      f32x2 pa_i = fma2(bc(a.w), sv, bc(a.y)*cv);
      f32x2 pb_r = fma2(bc(b.z), sv, bc(b.x)*cv);
      f32x2 pb_i = fma2(bc(b.w), sv, bc(b.y)*cv);
      bool bit = (lane >> j) & 1;
      f32x2 fr = bit ? pb_r : pa_r;
      f32x2 fi = bit ? pb_i : pa_i;
      if (j == 0){ lr = fr; li = fi; }
      else {
        f32x2 t = lr*fr - li*fi;
        li = fma2(lr, fi, li*fr);
        lr = t;
      }
    }
  }

  // parity-encoded qubit 4: n4 = popc(storage idx)&1 = popc(lane)&1 ^ popc(r)&1
  f32x2 A0r, A0i, A1r, A1i;
  {
    float angA = enc[(size_t)sA*NQ + 4] * invr;
    float angB = enc[(size_t)sB*NQ + 4] * invr;
    f32x2 cv = {__cosf(angA), __cosf(angB)};
    f32x2 sv = {__sinf(angA), __sinf(angB)};
    float4 a = U0[8], b = U0[9];
    f32x2 pa_r = fma2(bc(a.z), sv, bc(a.x)*cv);
    f32x2 pa_i = fma2(bc(a.w), sv, bc(a.y)*cv);
    f32x2 pb_r = fma2(bc(b.z), sv, bc(b.x)*cv);
    f32x2 pb_i = fma2(bc(b.w), sv, bc(b.y)*cv);
    bool e = __popc(lane) & 1;
    A0r = e ? pb_r : pa_r;  A0i = e ? pb_i : pa_i;
    A1r = e ? pa_r : pb_r;  A1i = e ? pa_i : pb_i;
  }

  // register-qubit product tree (logical 0..3 on reg bits 0..3)
  f32x2 re[16], im[16];
  re[0] = lr; im[0] = li;
  #pragma unroll
  for (int k = 0; k < 4; ++k){
    float angA = enc[(size_t)sA*NQ + k] * invr;
    float angB = enc[(size_t)sB*NQ + k] * invr;
    f32x2 cv = {__cosf(angA), __cosf(angB)};
    f32x2 sv = {__sinf(angA), __sinf(angB)};
    float4 a = U0[k*2+0], b = U0[k*2+1];
    f32x2 pa_r = fma2(bc(a.z), sv, bc(a.x)*cv);
    f32x2 pa_i = fma2(bc(a.w), sv, bc(a.y)*cv);
    f32x2 pb_r = fma2(bc(b.z), sv, bc(b.x)*cv);
    f32x2 pb_i = fma2(bc(b.w), sv, bc(b.y)*cv);
    int w = 1 << k;
    #pragma unroll
    for (int r = 0; r < 8; ++r) if (r < w){
      f32x2 xr = re[r], xi = im[r];
      re[r|w] = xr*pb_r - xi*pb_i;
      im[r|w] = fma2(xr, pb_i, xi*pb_r);
      re[r]   = xr*pa_r - xi*pa_i;
      im[r]   = fma2(xr, pa_i, xi*pa_r);
    }
  }
  // fold in the parity qubit factor (selection is compile-time per r)
  #pragma unroll
  for (int r = 0; r < 16; ++r){
    f32x2 sr = (__builtin_popcount(r) & 1) ? A1r : A0r;
    f32x2 si = (__builtin_popcount(r) & 1) ? A1i : A0i;
    f32x2 xr = re[r], xi = im[r];
    re[r] = xr*sr - xi*si;
    im[r] = fma2(xr, si, xi*sr);
  }

  run_layer<1>(re, im, gcT, phase4, lane);
  run_layer<2>(re, im, gcT, phase4, lane);
  run_layer<3>(re, im, gcT, phase4, lane);
  run_layer<4>(re, im, gcT, phase4, lane);
  run_layer<5>(re, im, gcT, phase4, lane);

  // probabilities -> 16-point WHT over register bits (packed)
  f32x2 p2[16];
  #pragma unroll
  for (int r = 0; r < 16; ++r) p2[r] = fma2(re[r], re[r], im[r]*im[r]);
  #pragma unroll
  for (int k = 0; k < 4; ++k){
    int w = 1 << k;
    #pragma unroll
    for (int r = 0; r < 16; ++r) if (!(r & w)){
      f32x2 a = p2[r], b = p2[r|w];
      p2[r] = a + b; p2[r|w] = a - b;
    }
  }
  // z_q partial = +/- p2[Rs&15], sign from storage lane bits; fuse FC
  f32x2 o2[4] = {{0.f,0.f},{0.f,0.f},{0.f,0.f},{0.f,0.f}};
  #pragma unroll
  for (int q = 0; q < NQ; ++q){
    constexpr int RALL[NQ] = {FT(TAB.meas[0]),FT(TAB.meas[1]),FT(TAB.meas[2]),
                              FT(TAB.meas[3]),FT(TAB.meas[4]),FT(TAB.meas[5]),
                              FT(TAB.meas[6]),FT(TAB.meas[7]),FT(TAB.meas[8]),
                              FT(TAB.meas[9])};
    int R = RALL[q];
    f32x2 tq = p2[R & 15];
    unsigned sg = (unsigned)(__popc((R >> 4) & lane) << 31);
    tq.x = __uint_as_float(__float_as_uint(tq.x) ^ sg);
    tq.y = __uint_as_float(__float_as_uint(tq.y) ^ sg);
    #pragma unroll
    for (int j = 0; j < 4; ++j) o2[j] = fma2(tq, bc(fcWs[j*NQ + q]), o2[j]);
  }
  #pragma unroll
  for (int j = 0; j < 4; ++j){
    #pragma unroll
    for (int st = 1; st < 64; st <<= 1){
      o2[j].x += __shfl_xor(o2[j].x, st, 64);
      o2[j].y += __shfl_xor(o2[j].y, st, 64);
    }
  }
  if (lane == 0){
    float4 a4 = make_float4(o2[0].x+fcB[0], o2[1].x+fcB[1], o2[2].x+fcB[2], o2[3].x+fcB[3]);
    float4 b4 = make_float4(o2[0].y+fcB[0], o2[1].y+fcB[1], o2[2].y+fcB[2], o2[3].y+fcB[3]);
    *reinterpret_cast<float4*>(&outB[(size_t)sA*4]) = a4;
    *reinterpret_cast<float4*>(&outB[(size_t)sB*4]) = b4;
  }
}

// ---- K3: deterministic BN stats (single block) ----
__global__ __launch_bounds__(1024) void k3_stats(const float* __restrict__ outB,
                                                 float* __restrict__ stats)
{
  int tid = threadIdx.x;
  float sum[4] = {0,0,0,0}, sq[4] = {0,0,0,0};
  for (int row = tid; row < B_SZ; row += 1024){
    float4 v = *reinterpret_cast<const float4*>(outB + (size_t)row*4);
    sum[0]+=v.x; sq[0]+=v.x*v.x;
    sum[1]+=v.y; sq[1]+=v.y*v.y;
    sum[2]+=v.z; sq[2]+=v.z*v.z;
    sum[3]+=v.w; sq[3]+=v.w*v.w;
  }
  #pragma unroll
  for (int k = 0; k < 4; ++k){
    #pragma unroll
    for (int st = 1; st < 64; st <<= 1){
      sum[k] += __shfl_xor(sum[k], st, 64);
      sq[k]  += __shfl_xor(sq[k],  st, 64);
    }
  }
  __shared__ float ls[16][8];
  int lane = tid & 63, w = tid >> 6;
  if (lane == 0){
    #pragma unroll
    for (int k = 0; k < 4; ++k){ ls[w][k] = sum[k]; ls[w][4+k] = sq[k]; }
  }
  __syncthreads();
  if (tid == 0){
    float fs[8];
    #pragma unroll
    for (int k = 0; k < 8; ++k){
      float a = 0.f;
      for (int w2 = 0; w2 < 16; ++w2) a += ls[w2][k];
      fs[k] = a;
    }
    #pragma unroll
    for (int k = 0; k < 4; ++k){
      float mean = fs[k] * (1.f/B_SZ);
      float var  = fs[4+k] * (1.f/B_SZ) - mean*mean;
      stats[k]   = mean;
      stats[4+k] = rsqrtf(var + 1e-5f);
    }
  }
}

// ---- K4: apply BN ----
__global__ __launch_bounds__(256) void k4_bn(const float* __restrict__ outB,
    const float* __restrict__ stats, const float* __restrict__ gamma,
    const float* __restrict__ beta, float* __restrict__ out)
{
  int idx = blockIdx.x * 256 + threadIdx.x;
  int c = idx & 3;
  float v = outB[idx];
  out[idx] = gamma[c] * (v - stats[c]) * stats[4+c] + beta[c];
}

extern "C" void kernel_launch(void* const* d_in, const int* in_sizes, int n_in,
                              void* d_out, int out_size, void* d_ws, size_t ws_size,
                              hipStream_t stream)
{
  const float* x     = (const float*)d_in[0];
  const float* encW  = (const float*)d_in[1];
  const float* encB  = (const float*)d_in[2];
  const float* wts   = (const float*)d_in[3];
  const float* fcW   = (const float*)d_in[4];
  const float* fcB   = (const float*)d_in[5];
  const float* gamma = (const float*)d_in[6];
  const float* beta  = (const float*)d_in[7];

  char* ws = (char*)d_ws;
  unsigned* gkey  = (unsigned*)ws;                      // 4 B
  float4*  U0     = (float4*)(ws + 256);                // 320 B
  float*   gcT    = (float*)(ws + 1024);                // 200 B
  float*   fcWs   = (float*)(ws + 2048);                // 160 B
  float4*  phase  = (float4*)(ws + 4096);               // 64 KB (c,c,s,s)
  float*   enc    = (float*)(ws + 4096 + 65536);
  float*   outB   = (float*)(ws + 4096 + 65536 + (size_t)B_SZ*NQ*4);
  float*   stats  = (float*)(ws + 4096 + 65536 + (size_t)B_SZ*NQ*4 + (size_t)B_SZ*4*4);

  hipLaunchKernelGGL(k_prep, dim3(16), dim3(256), 0, stream, wts, fcW, U0, gcT, phase, fcWs, gkey);
  hipLaunchKernelGGL(k1_encode, dim3(B_SZ/16), dim3(256), 0, stream,
                     x, encW, encB, enc, gkey);
  hipLaunchKernelGGL(k2_qsim, dim3(B_SZ/8), dim3(256), 0, stream,
                     enc, gkey, U0, gcT, phase, fcWs, fcB, outB);
  hipLaunchKernelGGL(k3_stats, dim3(1), dim3(1024), 0, stream, outB, stats);
  hipLaunchKernelGGL(k4_bn, dim3(B_SZ*4/256), dim3(256), 0, stream,
                     outB, stats, gamma, beta, (float*)d_out);
}